// Round 1
// baseline (529.705 us; speedup 1.0000x reference)
//
#include <hip/hip_runtime.h>

typedef __bf16 bf16;
typedef __bf16 bf16x8 __attribute__((ext_vector_type(8)));
typedef __bf16 bf16x4 __attribute__((ext_vector_type(4)));
typedef float f32x4 __attribute__((ext_vector_type(4)));

#define MFMA(a, b, c) __builtin_amdgcn_mfma_f32_16x16x32_bf16(a, b, c, 0, 0, 0)

// ---------------- fp32 -> bf16 weight convert ----------------
__global__ __launch_bounds__(256) void k_cvt(const float* __restrict__ src,
                                             bf16* __restrict__ dst, int n4) {
  int i = blockIdx.x * 256 + threadIdx.x;
  if (i < n4) {
    float4 v = ((const float4*)src)[i];
    bf16x4 o;
    o[0] = (bf16)v.x; o[1] = (bf16)v.y; o[2] = (bf16)v.z; o[3] = (bf16)v.w;
    ((bf16x4*)dst)[i] = o;
  }
}

// ---------------- dynamic position-bias MLP (961 rows) ----------------
__device__ __forceinline__ void lnrelu16(const float* in, float* out,
                                         const float* __restrict__ g,
                                         const float* __restrict__ b) {
  float mu = 0.f;
#pragma unroll
  for (int t = 0; t < 16; ++t) mu += in[t];
  mu *= 0.0625f;
  float var = 0.f;
#pragma unroll
  for (int t = 0; t < 16; ++t) { float d = in[t] - mu; var += d * d; }
  var *= 0.0625f;
  float inv = rsqrtf(var + 1e-5f);
#pragma unroll
  for (int t = 0; t < 16; ++t) {
    float v = (in[t] - mu) * inv * g[t] + b[t];
    out[t] = fmaxf(v, 0.f);
  }
}

__global__ __launch_bounds__(256) void k_dpb(
    const float* __restrict__ ppw, const float* __restrict__ ppb,
    const float* __restrict__ g1, const float* __restrict__ b1,
    const float* __restrict__ f1w, const float* __restrict__ f1b,
    const float* __restrict__ g2, const float* __restrict__ b2,
    const float* __restrict__ f2w, const float* __restrict__ f2b,
    const float* __restrict__ g3, const float* __restrict__ b3,
    const float* __restrict__ f3w, const float* __restrict__ f3b,
    float* __restrict__ ptab) {
  int l = blockIdx.x * 256 + threadIdx.x;
  if (l >= 961) return;
  float dh = (float)(l / 31) - 15.f;
  float dw = (float)(l % 31) - 15.f;
  float p[16], a[16], y[16];
#pragma unroll
  for (int t = 0; t < 16; ++t) p[t] = dh * ppw[2 * t] + dw * ppw[2 * t + 1] + ppb[t];
  lnrelu16(p, a, g1, b1);
#pragma unroll
  for (int t = 0; t < 16; ++t) {
    float s = f1b[t];
#pragma unroll
    for (int u = 0; u < 16; ++u) s += a[u] * f1w[t * 16 + u];
    y[t] = s;
  }
  lnrelu16(y, a, g2, b2);
#pragma unroll
  for (int t = 0; t < 16; ++t) {
    float s = f2b[t];
#pragma unroll
    for (int u = 0; u < 16; ++u) s += a[u] * f2w[t * 16 + u];
    p[t] = s;
  }
  lnrelu16(p, a, g3, b3);
#pragma unroll
  for (int t = 0; t < 8; ++t) {
    float s = f3b[t];
#pragma unroll
    for (int u = 0; u < 16; ++u) s += a[u] * f3w[t * 16 + u];
    ptab[l * 8 + t] = s;
  }
}

// ---------------- qkv GEMM: (B*N,256) x (768,256)^T ----------------
// block = (b, n-half); wave handles 2 n-tiles of 16. A-frags gathered from
// global x (b, c, n) — per instr 4 fully-used 64B lines; x read exactly once.
__global__ __launch_bounds__(256) void k_qkv(
    const float* __restrict__ x, const bf16* __restrict__ Wb,
    const float* __restrict__ qb, bf16* __restrict__ q, bf16* __restrict__ kk,
    bf16* __restrict__ vT) {
  const int b = blockIdx.x >> 1;
  const int nh = blockIdx.x & 1;
  const int lane = threadIdx.x & 63;
  const int wave = threadIdx.x >> 6;
  const int l15 = lane & 15, l4 = lane >> 4;
  const int n0 = nh * 128 + wave * 32;
  const float* xb = x + b * 65536;

  bf16x8 af[2][8];  // [n-tile][k-step], A row = l15 (=n), k = l4*8+j (=c)
#pragma unroll
  for (int nt = 0; nt < 2; ++nt) {
    int n = n0 + nt * 16 + l15;
#pragma unroll
    for (int kc = 0; kc < 8; ++kc) {
      int c0 = kc * 32 + l4 * 8;
      bf16x8 aa;
#pragma unroll
      for (int j = 0; j < 8; ++j) aa[j] = (bf16)xb[(c0 + j) * 256 + n];
      af[nt][kc] = aa;
    }
  }
  const f32x4 fz = {0.f, 0.f, 0.f, 0.f};
  for (int ot = 0; ot < 48; ++ot) {
    int o = ot * 16 + l15;  // B col = l15
    f32x4 acc0 = fz, acc1 = fz;
    const bf16* wr = Wb + o * 256 + l4 * 8;
#pragma unroll
    for (int kc = 0; kc < 8; ++kc) {
      bf16x8 bfr = *(const bf16x8*)(wr + kc * 32);
      acc0 = MFMA(af[0][kc], bfr, acc0);
      acc1 = MFMA(af[1][kc], bfr, acc1);
    }
    // D: row n = (l4*4 + r), col o = l15
    float bias = qb[o];
    int seg = o >> 8;
    int h = (o >> 5) & 7;
    int d = o & 31;
    int base = (b * 8 + h) * 8192;
    if (seg == 0) {
      bf16* dq = q + base + d;
#pragma unroll
      for (int nt = 0; nt < 2; ++nt)
#pragma unroll
        for (int r = 0; r < 4; ++r) {
          int n = n0 + nt * 16 + l4 * 4 + r;
          float v = nt ? acc1[r] : acc0[r];
          dq[n * 32] = (bf16)((v + bias) * 0.17677669529663687f);
        }
    } else if (seg == 1) {
      bf16* dk = kk + base + d;
#pragma unroll
      for (int nt = 0; nt < 2; ++nt)
#pragma unroll
        for (int r = 0; r < 4; ++r) {
          int n = n0 + nt * 16 + l4 * 4 + r;
          float v = nt ? acc1[r] : acc0[r];
          dk[n * 32] = (bf16)(v + bias);
        }
    } else {
      bf16* dv = vT + base + d * 256;  // transposed: (b,h,d,n)
#pragma unroll
      for (int nt = 0; nt < 2; ++nt) {
        bf16x4 pk;
#pragma unroll
        for (int r = 0; r < 4; ++r) {
          float v = nt ? acc1[r] : acc0[r];
          pk[r] = (bf16)(v + bias);
        }
        *(bf16x4*)(dv + n0 + nt * 16 + l4 * 4) = pk;
      }
    }
  }
}

// ---------------- attention per (b, h) ----------------
__global__ __launch_bounds__(256) void k_attn(
    const bf16* __restrict__ q, const bf16* __restrict__ kk,
    const bf16* __restrict__ vT, const float* __restrict__ ptab,
    bf16* __restrict__ ao) {
  __shared__ bf16 Kl[256 * 40];      // K rows padded 32->40 to spread banks
  __shared__ bf16 Vl[32 * 264];      // V^T rows padded 256->264
  __shared__ bf16 Pl[4][16 * 264];   // per-wave P tile
  const int bh = blockIdx.x;
  const int b = bh >> 3, h = bh & 7;
  const int tid = threadIdx.x;
  const int lane = tid & 63, wave = tid >> 6;
  const int l15 = lane & 15, l4 = lane >> 4;

  const bf16* Kg = kk + bh * 8192;
#pragma unroll
  for (int i = 0; i < 4; ++i) {
    int t = tid + i * 256;
    int n = t >> 2, dc = t & 3;
    *(bf16x8*)(Kl + n * 40 + dc * 8) = *(const bf16x8*)(Kg + n * 32 + dc * 8);
  }
  const bf16* Vg = vT + bh * 8192;
#pragma unroll
  for (int i = 0; i < 4; ++i) {
    int t = tid + i * 256;
    int d = t >> 5, nc = t & 31;
    *(bf16x8*)(Vl + d * 264 + nc * 8) = *(const bf16x8*)(Vg + d * 256 + nc * 8);
  }
  __syncthreads();

  const f32x4 fz = {0.f, 0.f, 0.f, 0.f};
  bf16* pw = Pl[wave];
  for (int qt = 0; qt < 4; ++qt) {
    const int q0 = wave * 64 + qt * 16;
    bf16x8 qf = *(const bf16x8*)(q + bh * 8192 + (q0 + l15) * 32 + l4 * 8);
    f32x4 s[16];
#pragma unroll
    for (int kt = 0; kt < 16; ++kt) {
      bf16x8 kf = *(const bf16x8*)(Kl + (kt * 16 + l15) * 40 + l4 * 8);
      s[kt] = MFMA(qf, kf, fz);  // S[n][key]: n=(l4*4+r), key=kt*16+l15
    }
    // + relative position bias (inline rel-index), then row softmax
#pragma unroll
    for (int r = 0; r < 4; ++r) {
      int n = q0 + l4 * 4 + r;
      int i1 = n >> 4, j1 = n & 15;
#pragma unroll
      for (int kt = 0; kt < 16; ++kt) {
        int li = (i1 - kt + 15) * 31 + (j1 - l15 + 15);
        s[kt][r] += ptab[li * 8 + h];
      }
      float m = s[0][r];
#pragma unroll
      for (int kt = 1; kt < 16; ++kt) m = fmaxf(m, s[kt][r]);
#pragma unroll
      for (int st = 1; st < 16; st <<= 1) m = fmaxf(m, __shfl_xor(m, st));
      float sum = 0.f;
#pragma unroll
      for (int kt = 0; kt < 16; ++kt) {
        float e = __expf(s[kt][r] - m);
        s[kt][r] = e;
        sum += e;
      }
#pragma unroll
      for (int st = 1; st < 16; st <<= 1) sum += __shfl_xor(sum, st);
      float inv = 1.f / sum;
#pragma unroll
      for (int kt = 0; kt < 16; ++kt) s[kt][r] *= inv;
    }
    // P -> LDS (bf16), then PV
#pragma unroll
    for (int kt = 0; kt < 16; ++kt)
#pragma unroll
      for (int r = 0; r < 4; ++r)
        pw[(l4 * 4 + r) * 264 + kt * 16 + l15] = (bf16)s[kt][r];
    f32x4 o0 = fz, o1 = fz;
#pragma unroll
    for (int ks = 0; ks < 8; ++ks) {
      bf16x8 pf = *(const bf16x8*)(pw + l15 * 264 + ks * 32 + l4 * 8);
      bf16x8 v0 = *(const bf16x8*)(Vl + l15 * 264 + ks * 32 + l4 * 8);
      bf16x8 v1 = *(const bf16x8*)(Vl + (16 + l15) * 264 + ks * 32 + l4 * 8);
      o0 = MFMA(pf, v0, o0);
      o1 = MFMA(pf, v1, o1);
    }
    bf16* aob = ao + (b * 256 + q0) * 256 + h * 32;
#pragma unroll
    for (int r = 0; r < 4; ++r) {
      int row = (l4 * 4 + r) * 256;
      aob[row + l15] = (bf16)o0[r];
      aob[row + 16 + l15] = (bf16)o1[r];
    }
  }
}

// ---------------- output projection, written transposed (b, o, n) ----------------
__global__ __launch_bounds__(256) void k_proj(
    const bf16* __restrict__ ao, const bf16* __restrict__ Wp,
    const float* __restrict__ pb, float* __restrict__ out) {
  const int blk = blockIdx.x;
  const int b = blk >> 2, oc = blk & 3;
  const int lane = threadIdx.x & 63, wave = threadIdx.x >> 6;
  const int l15 = lane & 15, l4 = lane >> 4;
  const int otile = oc * 4 + wave;
  bf16x8 af[8];  // A = proj_w: row o = l15, k = c
  const bf16* wr = Wp + (otile * 16 + l15) * 256 + l4 * 8;
#pragma unroll
  for (int kc = 0; kc < 8; ++kc) af[kc] = *(const bf16x8*)(wr + kc * 32);
  float bias[4];
#pragma unroll
  for (int r = 0; r < 4; ++r) bias[r] = pb[otile * 16 + l4 * 4 + r];
  const bf16* aob = ao + b * 65536;
  float* outb = out + b * 65536 + otile * 16 * 256;
  const f32x4 fz = {0.f, 0.f, 0.f, 0.f};
  for (int nt = 0; nt < 16; ++nt) {
    f32x4 acc = fz;
#pragma unroll
    for (int kc = 0; kc < 8; ++kc) {
      bf16x8 bfr = *(const bf16x8*)(aob + (nt * 16 + l15) * 256 + kc * 32 + l4 * 8);
      acc = MFMA(af[kc], bfr, acc);
    }
    // D: row = o_local = l4*4+r, col = n = l15 -> coalesced fp32 stores
#pragma unroll
    for (int r = 0; r < 4; ++r)
      outb[(l4 * 4 + r) * 256 + nt * 16 + l15] = acc[r] + bias[r];
  }
}

extern "C" void kernel_launch(void* const* d_in, const int* in_sizes, int n_in,
                              void* d_out, int out_size, void* d_ws, size_t ws_size,
                              hipStream_t stream) {
  const float* x    = (const float*)d_in[0];
  const float* qkvw = (const float*)d_in[1];
  const float* qkvb = (const float*)d_in[2];
  const float* pjw  = (const float*)d_in[3];
  const float* pjb  = (const float*)d_in[4];
  const float* ppw  = (const float*)d_in[5];
  const float* ppb  = (const float*)d_in[6];
  const float* g1 = (const float*)d_in[7];   const float* b1 = (const float*)d_in[8];
  const float* f1w = (const float*)d_in[9];  const float* f1b = (const float*)d_in[10];
  const float* g2 = (const float*)d_in[11];  const float* b2 = (const float*)d_in[12];
  const float* f2w = (const float*)d_in[13]; const float* f2b = (const float*)d_in[14];
  const float* g3 = (const float*)d_in[15];  const float* b3 = (const float*)d_in[16];
  const float* f3w = (const float*)d_in[17]; const float* f3b = (const float*)d_in[18];
  float* out = (float*)d_out;

  // workspace layout (bytes): q 33.5M | k 33.5M | vT 33.5M | ao 33.5M | ptab 32K | Wqkv 384K | Wproj 128K
  bf16* wsq  = (bf16*)d_ws;
  bf16* wsk  = wsq + 16777216;
  bf16* wsv  = wsk + 16777216;
  bf16* wsao = wsv + 16777216;
  float* ptab = (float*)(wsao + 16777216);
  bf16* wqkv = (bf16*)(ptab + 8192);
  bf16* wpj  = wqkv + 196608;

  hipLaunchKernelGGL(k_cvt, dim3(192), dim3(256), 0, stream, qkvw, wqkv, 49152);
  hipLaunchKernelGGL(k_cvt, dim3(64), dim3(256), 0, stream, pjw, wpj, 16384);
  hipLaunchKernelGGL(k_dpb, dim3(4), dim3(256), 0, stream, ppw, ppb, g1, b1, f1w,
                     f1b, g2, b2, f2w, f2b, g3, b3, f3w, f3b, ptab);
  hipLaunchKernelGGL(k_qkv, dim3(512), dim3(256), 0, stream, x, wqkv, qkvb, wsq,
                     wsk, wsv);
  hipLaunchKernelGGL(k_attn, dim3(2048), dim3(256), 0, stream, wsq, wsk, wsv,
                     ptab, wsao);
  hipLaunchKernelGGL(k_proj, dim3(1024), dim3(256), 0, stream, wsao, wpj, pjb, out);
}

// Round 2
// 340.378 us; speedup vs baseline: 1.5562x; 1.5562x over previous
//
#include <hip/hip_runtime.h>

typedef __bf16 bf16;
typedef __bf16 bf16x8 __attribute__((ext_vector_type(8)));
typedef __bf16 bf16x4 __attribute__((ext_vector_type(4)));
typedef float f32x4 __attribute__((ext_vector_type(4)));

#define MFMA(a, b, c) __builtin_amdgcn_mfma_f32_16x16x32_bf16(a, b, c, 0, 0, 0)

// ---------------- fp32 -> bf16 weight convert ----------------
__global__ __launch_bounds__(256) void k_cvt(const float* __restrict__ src,
                                             bf16* __restrict__ dst, int n4) {
  int i = blockIdx.x * 256 + threadIdx.x;
  if (i < n4) {
    float4 v = ((const float4*)src)[i];
    bf16x4 o;
    o[0] = (bf16)v.x; o[1] = (bf16)v.y; o[2] = (bf16)v.z; o[3] = (bf16)v.w;
    ((bf16x4*)dst)[i] = o;
  }
}

// ---------------- dynamic position-bias MLP (961 rows) ----------------
__device__ __forceinline__ void lnrelu16(const float* in, float* out,
                                         const float* __restrict__ g,
                                         const float* __restrict__ b) {
  float mu = 0.f;
#pragma unroll
  for (int t = 0; t < 16; ++t) mu += in[t];
  mu *= 0.0625f;
  float var = 0.f;
#pragma unroll
  for (int t = 0; t < 16; ++t) { float d = in[t] - mu; var += d * d; }
  var *= 0.0625f;
  float inv = rsqrtf(var + 1e-5f);
#pragma unroll
  for (int t = 0; t < 16; ++t) {
    float v = (in[t] - mu) * inv * g[t] + b[t];
    out[t] = fmaxf(v, 0.f);
  }
}

__global__ __launch_bounds__(256) void k_dpb(
    const float* __restrict__ ppw, const float* __restrict__ ppb,
    const float* __restrict__ g1, const float* __restrict__ b1,
    const float* __restrict__ f1w, const float* __restrict__ f1b,
    const float* __restrict__ g2, const float* __restrict__ b2,
    const float* __restrict__ f2w, const float* __restrict__ f2b,
    const float* __restrict__ g3, const float* __restrict__ b3,
    const float* __restrict__ f3w, const float* __restrict__ f3b,
    float* __restrict__ ptab) {
  int l = blockIdx.x * 256 + threadIdx.x;
  if (l >= 961) return;
  float dh = (float)(l / 31) - 15.f;
  float dw = (float)(l % 31) - 15.f;
  float p[16], a[16], y[16];
#pragma unroll
  for (int t = 0; t < 16; ++t) p[t] = dh * ppw[2 * t] + dw * ppw[2 * t + 1] + ppb[t];
  lnrelu16(p, a, g1, b1);
#pragma unroll
  for (int t = 0; t < 16; ++t) {
    float s = f1b[t];
#pragma unroll
    for (int u = 0; u < 16; ++u) s += a[u] * f1w[t * 16 + u];
    y[t] = s;
  }
  lnrelu16(y, a, g2, b2);
#pragma unroll
  for (int t = 0; t < 16; ++t) {
    float s = f2b[t];
#pragma unroll
    for (int u = 0; u < 16; ++u) s += a[u] * f2w[t * 16 + u];
    p[t] = s;
  }
  lnrelu16(p, a, g3, b3);
#pragma unroll
  for (int t = 0; t < 8; ++t) {
    float s = f3b[t];
#pragma unroll
    for (int u = 0; u < 16; ++u) s += a[u] * f3w[t * 16 + u];
    ptab[l * 8 + t] = s;
  }
}

// ---------------- bias table in MFMA C-fragment order ----------------
// Bsw[h][qt][kt][lane][r] (bf16): value = rpb[h][n=qt*16+l4*4+r][key=kt*16+l15]
__global__ __launch_bounds__(256) void k_bias(const float* __restrict__ ptab,
                                              bf16* __restrict__ Bsw) {
  int idx = blockIdx.x * 256 + threadIdx.x;  // 512 blocks -> 131072 threads
  int ft = idx >> 6;                         // tile id 0..2047 = ((h*16+qt)*16+kt)
  int lane = idx & 63;
  int h = ft >> 8, qt = (ft >> 4) & 15, kt = ft & 15;
  int l15 = lane & 15, l4 = lane >> 4;
  bf16x4 v;
#pragma unroll
  for (int r = 0; r < 4; ++r) {
    int li = (qt - kt + 15) * 31 + (l4 * 4 + r - l15 + 15);
    v[r] = (bf16)ptab[li * 8 + h];
  }
  *(bf16x4*)(Bsw + ft * 256 + lane * 4) = v;
}

// ---------------- qkv GEMM: (B*N,256) x (768,256)^T ----------------
__global__ __launch_bounds__(256) void k_qkv(
    const float* __restrict__ x, const bf16* __restrict__ Wb,
    const float* __restrict__ qb, bf16* __restrict__ q, bf16* __restrict__ kk,
    bf16* __restrict__ vT) {
  const int b = blockIdx.x >> 1;
  const int nh = blockIdx.x & 1;
  const int lane = threadIdx.x & 63;
  const int wave = threadIdx.x >> 6;
  const int l15 = lane & 15, l4 = lane >> 4;
  const int n0 = nh * 128 + wave * 32;
  const float* xb = x + b * 65536;

  bf16x8 af[2][8];  // [n-tile][k-step], A row = l15 (=n), k = l4*8+j (=c)
#pragma unroll
  for (int nt = 0; nt < 2; ++nt) {
    int n = n0 + nt * 16 + l15;
#pragma unroll
    for (int kc = 0; kc < 8; ++kc) {
      int c0 = kc * 32 + l4 * 8;
      bf16x8 aa;
#pragma unroll
      for (int j = 0; j < 8; ++j) aa[j] = (bf16)xb[(c0 + j) * 256 + n];
      af[nt][kc] = aa;
    }
  }
  const f32x4 fz = {0.f, 0.f, 0.f, 0.f};
  for (int ot = 0; ot < 48; ++ot) {
    int o = ot * 16 + l15;  // B col = l15
    f32x4 acc0 = fz, acc1 = fz;
    const bf16* wr = Wb + o * 256 + l4 * 8;
#pragma unroll
    for (int kc = 0; kc < 8; ++kc) {
      bf16x8 bfr = *(const bf16x8*)(wr + kc * 32);
      acc0 = MFMA(af[0][kc], bfr, acc0);
      acc1 = MFMA(af[1][kc], bfr, acc1);
    }
    // D: row n = (l4*4 + r), col o = l15
    float bias = qb[o];
    int seg = o >> 8;
    int h = (o >> 5) & 7;
    int d = o & 31;
    int base = (b * 8 + h) * 8192;
    if (seg == 0) {
      bf16* dq = q + base + d;
#pragma unroll
      for (int nt = 0; nt < 2; ++nt)
#pragma unroll
        for (int r = 0; r < 4; ++r) {
          int n = n0 + nt * 16 + l4 * 4 + r;
          float v = nt ? acc1[r] : acc0[r];
          dq[n * 32] = (bf16)((v + bias) * 0.17677669529663687f);
        }
    } else if (seg == 1) {
      bf16* dk = kk + base + d;
#pragma unroll
      for (int nt = 0; nt < 2; ++nt)
#pragma unroll
        for (int r = 0; r < 4; ++r) {
          int n = n0 + nt * 16 + l4 * 4 + r;
          float v = nt ? acc1[r] : acc0[r];
          dk[n * 32] = (bf16)(v + bias);
        }
    } else {
      bf16* dv = vT + base + d * 256;  // transposed: (b,h,d,n)
#pragma unroll
      for (int nt = 0; nt < 2; ++nt) {
        bf16x4 pk;
#pragma unroll
        for (int r = 0; r < 4; ++r) {
          float v = nt ? acc1[r] : acc0[r];
          pk[r] = (bf16)(v + bias);
        }
        *(bf16x4*)(dv + n0 + nt * 16 + l4 * 4) = pk;
      }
    }
  }
}

// ---------------- attention per (b, h) ----------------
// LDS: K (pad 36, conflict-free) + per-wave P (pad 260). V^T read from L2.
__global__ __launch_bounds__(256, 3) void k_attn(
    const bf16* __restrict__ q, const bf16* __restrict__ kk,
    const bf16* __restrict__ vT, const bf16* __restrict__ Bsw,
    bf16* __restrict__ ao) {
  __shared__ bf16 Kl[256 * 36];     // 18,432 B
  __shared__ bf16 Pl[4][16 * 260];  // 33,280 B -> total 51,712 B, 3 blocks/CU
  const int bh = blockIdx.x;
  const int b = bh >> 3, h = bh & 7;
  const int tid = threadIdx.x;
  const int lane = tid & 63, wave = tid >> 6;
  const int l15 = lane & 15, l4 = lane >> 4;

  const bf16* Kg = kk + bh * 8192;
#pragma unroll
  for (int i = 0; i < 4; ++i) {
    int t = tid + i * 256;
    int n = t >> 2, dc = t & 3;
    *(bf16x8*)(Kl + n * 36 + dc * 8) = *(const bf16x8*)(Kg + n * 32 + dc * 8);
  }
  __syncthreads();

  const bf16* Vg = vT + bh * 8192;
  const bf16* Bh = Bsw + h * 65536;  // 16 qt x 16 kt x 64 lanes x 4
  bf16* pw = Pl[wave];
  const f32x4 fz = {0.f, 0.f, 0.f, 0.f};
  for (int qt = 0; qt < 4; ++qt) {
    const int q0 = wave * 64 + qt * 16;
    bf16x8 qf = *(const bf16x8*)(q + bh * 8192 + (q0 + l15) * 32 + l4 * 8);
    const bf16* Bq = Bh + (q0 >> 4) * 4096 + lane * 4;
    f32x4 s[16];
#pragma unroll
    for (int kt = 0; kt < 16; ++kt) {
      bf16x4 bb = *(const bf16x4*)(Bq + kt * 256);
      f32x4 ci;
#pragma unroll
      for (int j = 0; j < 4; ++j) ci[j] = (float)bb[j];
      bf16x8 kf = *(const bf16x8*)(Kl + (kt * 16 + l15) * 36 + l4 * 8);
      s[kt] = MFMA(qf, kf, ci);  // S[n][key]+bias: n=(l4*4+r), key=kt*16+l15
    }
    // row softmax: rows n = q0+l4*4+r, key distributed over 16 l15 lanes
#pragma unroll
    for (int r = 0; r < 4; ++r) {
      float m = s[0][r];
#pragma unroll
      for (int kt = 1; kt < 16; ++kt) m = fmaxf(m, s[kt][r]);
#pragma unroll
      for (int st = 1; st < 16; st <<= 1) m = fmaxf(m, __shfl_xor(m, st));
      float sum = 0.f;
#pragma unroll
      for (int kt = 0; kt < 16; ++kt) {
        float e = __expf(s[kt][r] - m);
        s[kt][r] = e;
        sum += e;
      }
#pragma unroll
      for (int st = 1; st < 16; st <<= 1) sum += __shfl_xor(sum, st);
      float inv = 1.f / sum;
#pragma unroll
      for (int kt = 0; kt < 16; ++kt) s[kt][r] *= inv;
    }
    // P -> LDS (bf16), then PV with V^T from global (L1/L2-resident)
#pragma unroll
    for (int kt = 0; kt < 16; ++kt)
#pragma unroll
      for (int r = 0; r < 4; ++r)
        pw[(l4 * 4 + r) * 260 + kt * 16 + l15] = (bf16)s[kt][r];
    f32x4 o0 = fz, o1 = fz;
#pragma unroll
    for (int ks = 0; ks < 8; ++ks) {
      bf16x8 pf = *(const bf16x8*)(pw + l15 * 260 + ks * 32 + l4 * 8);
      bf16x8 v0 = *(const bf16x8*)(Vg + l15 * 256 + ks * 32 + l4 * 8);
      bf16x8 v1 = *(const bf16x8*)(Vg + (16 + l15) * 256 + ks * 32 + l4 * 8);
      o0 = MFMA(pf, v0, o0);
      o1 = MFMA(pf, v1, o1);
    }
    bf16* aob = ao + (b * 256 + q0) * 256 + h * 32;
#pragma unroll
    for (int r = 0; r < 4; ++r) {
      int row = (l4 * 4 + r) * 256;
      aob[row + l15] = (bf16)o0[r];
      aob[row + 16 + l15] = (bf16)o1[r];
    }
  }
}

// ---------------- output projection, written transposed (b, o, n) ----------------
__global__ __launch_bounds__(256) void k_proj(
    const bf16* __restrict__ ao, const bf16* __restrict__ Wp,
    const float* __restrict__ pb, float* __restrict__ out) {
  // XCD-bijective swizzle: 4 consecutive flat ids (same b) land on one XCD
  const int i = blockIdx.x;
  const int flat = (i & 7) * 128 + (i >> 3);
  const int b = flat >> 2, oc = flat & 3;
  const int lane = threadIdx.x & 63, wave = threadIdx.x >> 6;
  const int l15 = lane & 15, l4 = lane >> 4;
  const int otile = oc * 4 + wave;
  bf16x8 af[8];  // A = proj_w: row o = l15, k = c
  const bf16* wr = Wp + (otile * 16 + l15) * 256 + l4 * 8;
#pragma unroll
  for (int kc = 0; kc < 8; ++kc) af[kc] = *(const bf16x8*)(wr + kc * 32);
  float bias[4];
#pragma unroll
  for (int r = 0; r < 4; ++r) bias[r] = pb[otile * 16 + l4 * 4 + r];
  const bf16* aob = ao + b * 65536;
  float* outb = out + b * 65536 + otile * 16 * 256;
  const f32x4 fz = {0.f, 0.f, 0.f, 0.f};
  for (int nt = 0; nt < 16; ++nt) {
    f32x4 acc = fz;
#pragma unroll
    for (int kc = 0; kc < 8; ++kc) {
      bf16x8 bfr = *(const bf16x8*)(aob + (nt * 16 + l15) * 256 + kc * 32 + l4 * 8);
      acc = MFMA(af[kc], bfr, acc);
    }
#pragma unroll
    for (int r = 0; r < 4; ++r)
      outb[(l4 * 4 + r) * 256 + nt * 16 + l15] = acc[r] + bias[r];
  }
}

extern "C" void kernel_launch(void* const* d_in, const int* in_sizes, int n_in,
                              void* d_out, int out_size, void* d_ws, size_t ws_size,
                              hipStream_t stream) {
  const float* x    = (const float*)d_in[0];
  const float* qkvw = (const float*)d_in[1];
  const float* qkvb = (const float*)d_in[2];
  const float* pjw  = (const float*)d_in[3];
  const float* pjb  = (const float*)d_in[4];
  const float* ppw  = (const float*)d_in[5];
  const float* ppb  = (const float*)d_in[6];
  const float* g1 = (const float*)d_in[7];   const float* b1 = (const float*)d_in[8];
  const float* f1w = (const float*)d_in[9];  const float* f1b = (const float*)d_in[10];
  const float* g2 = (const float*)d_in[11];  const float* b2 = (const float*)d_in[12];
  const float* f2w = (const float*)d_in[13]; const float* f2b = (const float*)d_in[14];
  const float* g3 = (const float*)d_in[15];  const float* b3 = (const float*)d_in[16];
  const float* f3w = (const float*)d_in[17]; const float* f3b = (const float*)d_in[18];
  float* out = (float*)d_out;

  // ws: q | k | vT | ao (16,777,216 bf16 each) | ptab 8192 f32 | Wqkv 196608 bf16
  //     | Wproj 65536 bf16 | Bsw 524288 bf16
  bf16* wsq  = (bf16*)d_ws;
  bf16* wsk  = wsq + 16777216;
  bf16* wsv  = wsk + 16777216;
  bf16* wsao = wsv + 16777216;
  float* ptab = (float*)(wsao + 16777216);
  bf16* wqkv = (bf16*)(ptab + 8192);
  bf16* wpj  = wqkv + 196608;
  bf16* bsw  = wpj + 65536;

  hipLaunchKernelGGL(k_cvt, dim3(192), dim3(256), 0, stream, qkvw, wqkv, 49152);
  hipLaunchKernelGGL(k_cvt, dim3(64), dim3(256), 0, stream, pjw, wpj, 16384);
  hipLaunchKernelGGL(k_dpb, dim3(4), dim3(256), 0, stream, ppw, ppb, g1, b1, f1w,
                     f1b, g2, b2, f2w, f2b, g3, b3, f3w, f3b, ptab);
  hipLaunchKernelGGL(k_bias, dim3(512), dim3(256), 0, stream, ptab, bsw);
  hipLaunchKernelGGL(k_qkv, dim3(512), dim3(256), 0, stream, x, wqkv, qkvb, wsq,
                     wsk, wsv);
  hipLaunchKernelGGL(k_attn, dim3(2048), dim3(256), 0, stream, wsq, wsk, wsv,
                     bsw, wsao);
  hipLaunchKernelGGL(k_proj, dim3(1024), dim3(256), 0, stream, wsao, wpj, pjb, out);
}

// Round 4
// 270.638 us; speedup vs baseline: 1.9572x; 1.2577x over previous
//
#include <hip/hip_runtime.h>

typedef __bf16 bf16;
typedef __bf16 bf16x8 __attribute__((ext_vector_type(8)));
typedef __bf16 bf16x4 __attribute__((ext_vector_type(4)));
typedef float f32x4 __attribute__((ext_vector_type(4)));
typedef float f32x16 __attribute__((ext_vector_type(16)));
typedef unsigned int u32;
typedef unsigned int u32x4 __attribute__((ext_vector_type(4)));

#define MFMA16(a, b, c) __builtin_amdgcn_mfma_f32_16x16x32_bf16(a, b, c, 0, 0, 0)
#define MFMA32(a, b, c) __builtin_amdgcn_mfma_f32_32x32x16_bf16(a, b, c, 0, 0, 0)

__device__ __forceinline__ u32 pack2(float a, float b) {
  unsigned short ua = __builtin_bit_cast(unsigned short, (bf16)a);
  unsigned short ub = __builtin_bit_cast(unsigned short, (bf16)b);
  return (u32)ua | ((u32)ub << 16);
}

// ---------------- fp32 -> bf16 weight convert ----------------
__global__ __launch_bounds__(256) void k_cvt(const float* __restrict__ src,
                                             bf16* __restrict__ dst, int n4) {
  int i = blockIdx.x * 256 + threadIdx.x;
  if (i < n4) {
    float4 v = ((const float4*)src)[i];
    bf16x4 o;
    o[0] = (bf16)v.x; o[1] = (bf16)v.y; o[2] = (bf16)v.z; o[3] = (bf16)v.w;
    ((bf16x4*)dst)[i] = o;
  }
}

// ---------------- dynamic position-bias MLP (961 rows) ----------------
__device__ __forceinline__ void lnrelu16(const float* in, float* out,
                                         const float* __restrict__ g,
                                         const float* __restrict__ b) {
  float mu = 0.f;
#pragma unroll
  for (int t = 0; t < 16; ++t) mu += in[t];
  mu *= 0.0625f;
  float var = 0.f;
#pragma unroll
  for (int t = 0; t < 16; ++t) { float d = in[t] - mu; var += d * d; }
  var *= 0.0625f;
  float inv = rsqrtf(var + 1e-5f);
#pragma unroll
  for (int t = 0; t < 16; ++t) {
    float v = (in[t] - mu) * inv * g[t] + b[t];
    out[t] = fmaxf(v, 0.f);
  }
}

__global__ __launch_bounds__(256) void k_dpb(
    const float* __restrict__ ppw, const float* __restrict__ ppb,
    const float* __restrict__ g1, const float* __restrict__ b1,
    const float* __restrict__ f1w, const float* __restrict__ f1b,
    const float* __restrict__ g2, const float* __restrict__ b2,
    const float* __restrict__ f2w, const float* __restrict__ f2b,
    const float* __restrict__ g3, const float* __restrict__ b3,
    const float* __restrict__ f3w, const float* __restrict__ f3b,
    float* __restrict__ ptab) {
  int l = blockIdx.x * 256 + threadIdx.x;
  if (l >= 961) return;
  float dh = (float)(l / 31) - 15.f;
  float dw = (float)(l % 31) - 15.f;
  float p[16], a[16], y[16];
#pragma unroll
  for (int t = 0; t < 16; ++t) p[t] = dh * ppw[2 * t] + dw * ppw[2 * t + 1] + ppb[t];
  lnrelu16(p, a, g1, b1);
#pragma unroll
  for (int t = 0; t < 16; ++t) {
    float s = f1b[t];
#pragma unroll
    for (int u = 0; u < 16; ++u) s += a[u] * f1w[t * 16 + u];
    y[t] = s;
  }
  lnrelu16(y, a, g2, b2);
#pragma unroll
  for (int t = 0; t < 16; ++t) {
    float s = f2b[t];
#pragma unroll
    for (int u = 0; u < 16; ++u) s += a[u] * f2w[t * 16 + u];
    p[t] = s;
  }
  lnrelu16(p, a, g3, b3);
#pragma unroll
  for (int t = 0; t < 8; ++t) {
    float s = f3b[t];
#pragma unroll
    for (int u = 0; u < 16; ++u) s += a[u] * f3w[t * 16 + u];
    ptab[l * 8 + t] = s;
  }
}

// ---------------- bias table in 32x32 MFMA D-fragment order ----------------
// Bsw[tg=(h*8+qt)*8+kt2][lane][reg] = rpb[h][n=qt*32+(lane&31)]
//                                        [key=kt2*32+(reg&3)+8*(reg>>2)+4*(lane>>5)]
__global__ __launch_bounds__(256) void k_bias(const float* __restrict__ ptab,
                                              bf16* __restrict__ Bsw) {
  int idx = blockIdx.x * 256 + threadIdx.x;  // 128 blocks -> 32768 threads
  int lane = idx & 63, tg = idx >> 6;        // tg 0..511
  int h = tg >> 6, qt = (tg >> 3) & 7, kt2 = tg & 7;
  int l31 = lane & 31, hi2 = lane >> 5;
  int n = qt * 32 + l31;
  int i1 = n >> 4, j1 = n & 15;
  bf16x8 o0, o1;
#pragma unroll
  for (int reg = 0; reg < 16; ++reg) {
    int key = kt2 * 32 + (reg & 3) + 8 * (reg >> 2) + 4 * hi2;
    int i2 = key >> 4, j2 = key & 15;
    int li = (i1 - i2 + 15) * 31 + (j1 - j2 + 15);
    bf16 v = (bf16)ptab[li * 8 + h];
    if (reg < 8) o0[reg] = v; else o1[reg - 8] = v;
  }
  bf16* dst = Bsw + tg * 1024 + lane * 16;
  *(bf16x8*)dst = o0;
  *(bf16x8*)(dst + 8) = o1;
}

// ---------------- qkv GEMM: (B*N,256) x (768,256)^T ----------------
// 512-thread blocks, 8 waves: wave = (ot-half, n-chunk) -> 16 waves/CU.
__global__ __launch_bounds__(512) void k_qkv(
    const float* __restrict__ x, const bf16* __restrict__ Wb,
    const float* __restrict__ qb, bf16* __restrict__ q, bf16* __restrict__ kk,
    bf16* __restrict__ vT) {
  __shared__ bf16 Vb[8][16 * 36];  // per-wave v transpose bounce
  const int b = blockIdx.x >> 1;
  const int nh = blockIdx.x & 1;
  const int tid = threadIdx.x;
  const int lane = tid & 63;
  const int wave = tid >> 6;
  const int wn = wave & 3, oh = wave >> 2;
  const int l15 = lane & 15, l4 = lane >> 4;
  const int n0 = nh * 128 + wn * 32;
  const float* xb = x + b * 65536;

  bf16x8 af[2][8];  // [n-tile][k-step], A row = l15 (=n), k = l4*8+j (=c)
#pragma unroll
  for (int nt = 0; nt < 2; ++nt) {
    int n = n0 + nt * 16 + l15;
#pragma unroll
    for (int kc = 0; kc < 8; ++kc) {
      int c0 = kc * 32 + l4 * 8;
      bf16x8 aa;
#pragma unroll
      for (int j = 0; j < 8; ++j) aa[j] = (bf16)xb[(c0 + j) * 256 + n];
      af[nt][kc] = aa;
    }
  }
  const f32x4 fz = {0.f, 0.f, 0.f, 0.f};
  bf16* lb = Vb[wave];
  for (int ot = oh * 24; ot < oh * 24 + 24; ++ot) {
    int o = ot * 16 + l15;  // B col = l15
    f32x4 acc0 = fz, acc1 = fz;
    const bf16* wr = Wb + o * 256 + l4 * 8;
#pragma unroll
    for (int kc = 0; kc < 8; ++kc) {
      bf16x8 bfr = *(const bf16x8*)(wr + kc * 32);
      acc0 = MFMA16(af[0][kc], bfr, acc0);
      acc1 = MFMA16(af[1][kc], bfr, acc1);
    }
    // D: row n = (l4*4 + r), col o = l15
    float bias = qb[o];
    int seg = o >> 8;
    int h = (o >> 5) & 7;
    int d = o & 31;
    int base = (b * 8 + h) * 8192;
    if (seg == 0) {
      bf16* dq = q + base + d;
#pragma unroll
      for (int nt = 0; nt < 2; ++nt)
#pragma unroll
        for (int r = 0; r < 4; ++r) {
          int n = n0 + nt * 16 + l4 * 4 + r;
          float v = nt ? acc1[r] : acc0[r];
          dq[n * 32] = (bf16)((v + bias) * 0.17677669529663687f);
        }
    } else if (seg == 1) {
      bf16* dk = kk + base + d;
#pragma unroll
      for (int nt = 0; nt < 2; ++nt)
#pragma unroll
        for (int r = 0; r < 4; ++r) {
          int n = n0 + nt * 16 + l4 * 4 + r;
          float v = nt ? acc1[r] : acc0[r];
          dk[n * 32] = (bf16)(v + bias);
        }
    } else {
      // v: transpose 16d x 32n tile through LDS -> contiguous-n 64B rows
#pragma unroll
      for (int nt = 0; nt < 2; ++nt) {
        f32x4 a = nt ? acc1 : acc0;
        *(u32*)(lb + l15 * 36 + nt * 16 + l4 * 4) = pack2(a[0] + bias, a[1] + bias);
        *(u32*)(lb + l15 * 36 + nt * 16 + l4 * 4 + 2) = pack2(a[2] + bias, a[3] + bias);
      }
      asm volatile("s_waitcnt lgkmcnt(0)" ::: "memory");
      __builtin_amdgcn_sched_barrier(0);
      int dl = lane >> 2, chv = lane & 3;
      bf16x4 rv0 = *(bf16x4*)(lb + dl * 36 + chv * 8);
      bf16x4 rv1 = *(bf16x4*)(lb + dl * 36 + chv * 8 + 4);
      asm volatile("s_waitcnt lgkmcnt(0)" ::: "memory");
      __builtin_amdgcn_sched_barrier(0);
      int d2 = (ot & 1) * 16 + dl;
      bf16* dv2 = vT + base + d2 * 256 + n0 + chv * 8;
      *(bf16x4*)dv2 = rv0;
      *(bf16x4*)(dv2 + 4) = rv1;
    }
  }
}

// ---------------- attention per (b, h): 32x32 swapped-operand scheme ----------------
// S^T = K·Q (MFMA 32x32x16): lane owns softmax column n in registers.
// PV B-frags built in-register via one half-wave swap per 16-key block.
__global__ __launch_bounds__(256, 2) void k_attn(
    const bf16* __restrict__ q, const bf16* __restrict__ kk,
    const bf16* __restrict__ vT, const bf16* __restrict__ Bsw,
    bf16* __restrict__ ao) {
  __shared__ bf16 Kl[256 * 36];    // 18,432 B
  __shared__ bf16 Ob[4][32 * 36];  // 9,216 B: per-wave output transpose bounce
  const int bh = blockIdx.x;
  const int b = bh >> 3, h = bh & 7;
  const int tid = threadIdx.x;
  const int lane = tid & 63, wave = tid >> 6;
  const int l31 = lane & 31, hi = lane >> 5;

  const bf16* Kg = kk + bh * 8192;
#pragma unroll
  for (int i = 0; i < 4; ++i) {
    int t = tid + i * 256;
    int n = t >> 2, dc = t & 3;
    *(bf16x8*)(Kl + n * 36 + dc * 8) = *(const bf16x8*)(Kg + n * 32 + dc * 8);
  }
  __syncthreads();

  const bf16* Vg = vT + bh * 8192;
  bf16* ob = Ob[wave];
  for (int qi = 0; qi < 2; ++qi) {
    const int qt = wave * 2 + qi, q0 = qt * 32;
    // Q B-frags: col = l31 = n, k = c = cs*16 + hi*8 + j
    bf16x8 qf0 = *(const bf16x8*)(q + bh * 8192 + (q0 + l31) * 32 + hi * 8);
    bf16x8 qf1 = *(const bf16x8*)(q + bh * 8192 + (q0 + l31) * 32 + 16 + hi * 8);
    const bf16* bq = Bsw + (h * 8 + qt) * 8192 + lane * 16;
    f32x16 s[8];
#pragma unroll
    for (int kt2 = 0; kt2 < 8; ++kt2) {
      bf16x8 ba = *(const bf16x8*)(bq + kt2 * 1024);
      bf16x8 bbv = *(const bf16x8*)(bq + kt2 * 1024 + 8);
      f32x16 acc;
#pragma unroll
      for (int i = 0; i < 8; ++i) {
        acc[i] = (float)ba[i];
        acc[8 + i] = (float)bbv[i];
      }
      // A-frag K: row = l31 = key_local, k = c
      bf16x8 kf0 = *(const bf16x8*)(Kl + (kt2 * 32 + l31) * 36 + hi * 8);
      bf16x8 kf1 = *(const bf16x8*)(Kl + (kt2 * 32 + l31) * 36 + 16 + hi * 8);
      acc = MFMA32(kf0, qf0, acc);
      acc = MFMA32(kf1, qf1, acc);
      s[kt2] = acc;  // S^T[key=kt2*32+(reg&3)+8*(reg>>2)+4*hi][n=q0+l31]
    }
    // softmax over the column (in-register + one half-wave swap)
    float m = -1e30f;
#pragma unroll
    for (int kt2 = 0; kt2 < 8; ++kt2)
#pragma unroll
      for (int i = 0; i < 16; ++i) m = fmaxf(m, s[kt2][i]);
    m = fmaxf(m, __shfl_xor(m, 32));
    float sum = 0.f;
#pragma unroll
    for (int kt2 = 0; kt2 < 8; ++kt2)
#pragma unroll
      for (int i = 0; i < 16; ++i) {
        float e = __expf(s[kt2][i] - m);
        s[kt2][i] = e;
        sum += e;
      }
    sum += __shfl_xor(sum, 32);
    const float inv = 1.f / sum;

    f32x16 o;
#pragma unroll
    for (int i = 0; i < 16; ++i) o[i] = 0.f;
#pragma unroll
    for (int kt2 = 0; kt2 < 8; ++kt2) {
      u32 lo[4], hw[4];
#pragma unroll
      for (int qq = 0; qq < 4; ++qq) {
        lo[qq] = pack2(s[kt2][4 * qq] * inv, s[kt2][4 * qq + 1] * inv);
        hw[qq] = pack2(s[kt2][4 * qq + 2] * inv, s[kt2][4 * qq + 3] * inv);
      }
#pragma unroll
      for (int sb = 0; sb < 2; ++sb) {
        // lane quad q=2sb+hi holds keys [16sb+8hi, +4); partner holds the rest
        u32 keep_lo = hi ? lo[2 * sb + 1] : lo[2 * sb];
        u32 keep_hi = hi ? hw[2 * sb + 1] : hw[2 * sb];
        u32 send_lo = hi ? lo[2 * sb] : lo[2 * sb + 1];
        u32 send_hi = hi ? hw[2 * sb] : hw[2 * sb + 1];
        u32 rlo = __shfl_xor(send_lo, 32);
        u32 rhi = __shfl_xor(send_hi, 32);
        u32x4 bw;
        bw[0] = hi ? rlo : keep_lo;
        bw[1] = hi ? rhi : keep_hi;
        bw[2] = hi ? keep_lo : rlo;
        bw[3] = hi ? keep_hi : rhi;
        bf16x8 pf = __builtin_bit_cast(bf16x8, bw);
        // V^T A-frag: row = l31 = d, k = key
        bf16x8 vf = *(const bf16x8*)(Vg + l31 * 256 + kt2 * 32 + sb * 16 + hi * 8);
        o = MFMA32(vf, pf, o);
      }
    }
    // O^T[d][n] -> transpose via per-wave LDS -> 64B-contiguous ao rows
#pragma unroll
    for (int qq = 0; qq < 4; ++qq) {
      *(u32*)(ob + l31 * 36 + 8 * qq + 4 * hi) = pack2(o[4 * qq], o[4 * qq + 1]);
      *(u32*)(ob + l31 * 36 + 8 * qq + 4 * hi + 2) = pack2(o[4 * qq + 2], o[4 * qq + 3]);
    }
    asm volatile("s_waitcnt lgkmcnt(0)" ::: "memory");
    __builtin_amdgcn_sched_barrier(0);
    int n2 = lane >> 1, ch = lane & 1;
    bf16x4 r0 = *(bf16x4*)(ob + n2 * 36 + ch * 16);
    bf16x4 r1 = *(bf16x4*)(ob + n2 * 36 + ch * 16 + 4);
    bf16x4 r2 = *(bf16x4*)(ob + n2 * 36 + ch * 16 + 8);
    bf16x4 r3 = *(bf16x4*)(ob + n2 * 36 + ch * 16 + 12);
    asm volatile("s_waitcnt lgkmcnt(0)" ::: "memory");
    __builtin_amdgcn_sched_barrier(0);
    bf16* dst = ao + (b * 256 + q0 + n2) * 256 + h * 32 + ch * 16;
    *(bf16x4*)dst = r0;
    *(bf16x4*)(dst + 4) = r1;
    *(bf16x4*)(dst + 8) = r2;
    *(bf16x4*)(dst + 12) = r3;
  }
}

// ---------------- output projection, written transposed (b, o, n) ----------------
__global__ __launch_bounds__(256) void k_proj(
    const bf16* __restrict__ ao, const bf16* __restrict__ Wp,
    const float* __restrict__ pb, float* __restrict__ out) {
  const int i = blockIdx.x;
  const int flat = (i & 7) * 128 + (i >> 3);  // XCD-bijective swizzle
  const int b = flat >> 2, oc = flat & 3;
  const int lane = threadIdx.x & 63, wave = threadIdx.x >> 6;
  const int l15 = lane & 15, l4 = lane >> 4;
  const int otile = oc * 4 + wave;
  bf16x8 af[8];  // A = proj_w: row o = l15, k = c
  const bf16* wr = Wp + (otile * 16 + l15) * 256 + l4 * 8;
#pragma unroll
  for (int kc = 0; kc < 8; ++kc) af[kc] = *(const bf16x8*)(wr + kc * 32);
  float bias[4];
#pragma unroll
  for (int r = 0; r < 4; ++r) bias[r] = pb[otile * 16 + l4 * 4 + r];
  const bf16* aob = ao + b * 65536;
  float* outb = out + b * 65536 + otile * 16 * 256;
  const f32x4 fz = {0.f, 0.f, 0.f, 0.f};
  for (int nt = 0; nt < 16; ++nt) {
    f32x4 acc = fz;
#pragma unroll
    for (int kc = 0; kc < 8; ++kc) {
      bf16x8 bfr = *(const bf16x8*)(aob + (nt * 16 + l15) * 256 + kc * 32 + l4 * 8);
      acc = MFMA16(af[kc], bfr, acc);
    }
#pragma unroll
    for (int r = 0; r < 4; ++r)
      outb[(l4 * 4 + r) * 256 + nt * 16 + l15] = acc[r] + bias[r];
  }
}

extern "C" void kernel_launch(void* const* d_in, const int* in_sizes, int n_in,
                              void* d_out, int out_size, void* d_ws, size_t ws_size,
                              hipStream_t stream) {
  const float* x    = (const float*)d_in[0];
  const float* qkvw = (const float*)d_in[1];
  const float* qkvb = (const float*)d_in[2];
  const float* pjw  = (const float*)d_in[3];
  const float* pjb  = (const float*)d_in[4];
  const float* ppw  = (const float*)d_in[5];
  const float* ppb  = (const float*)d_in[6];
  const float* g1 = (const float*)d_in[7];   const float* b1 = (const float*)d_in[8];
  const float* f1w = (const float*)d_in[9];  const float* f1b = (const float*)d_in[10];
  const float* g2 = (const float*)d_in[11];  const float* b2 = (const float*)d_in[12];
  const float* f2w = (const float*)d_in[13]; const float* f2b = (const float*)d_in[14];
  const float* g3 = (const float*)d_in[15];  const float* b3 = (const float*)d_in[16];
  const float* f3w = (const float*)d_in[17]; const float* f3b = (const float*)d_in[18];
  float* out = (float*)d_out;

  // ws: q | k | vT | ao (16,777,216 bf16 each) | ptab 8192 f32 | Wqkv 196608 bf16
  //     | Wproj 65536 bf16 | Bsw 524288 bf16
  bf16* wsq  = (bf16*)d_ws;
  bf16* wsk  = wsq + 16777216;
  bf16* wsv  = wsk + 16777216;
  bf16* wsao = wsv + 16777216;
  float* ptab = (float*)(wsao + 16777216);
  bf16* wqkv = (bf16*)(ptab + 8192);
  bf16* wpj  = wqkv + 196608;
  bf16* bsw  = wpj + 65536;

  hipLaunchKernelGGL(k_cvt, dim3(192), dim3(256), 0, stream, qkvw, wqkv, 49152);
  hipLaunchKernelGGL(k_cvt, dim3(64), dim3(256), 0, stream, pjw, wpj, 16384);
  hipLaunchKernelGGL(k_dpb, dim3(4), dim3(256), 0, stream, ppw, ppb, g1, b1, f1w,
                     f1b, g2, b2, f2w, f2b, g3, b3, f3w, f3b, ptab);
  hipLaunchKernelGGL(k_bias, dim3(128), dim3(256), 0, stream, ptab, bsw);
  hipLaunchKernelGGL(k_qkv, dim3(512), dim3(512), 0, stream, x, wqkv, qkvb, wsq,
                     wsk, wsv);
  hipLaunchKernelGGL(k_attn, dim3(2048), dim3(256), 0, stream, wsq, wsk, wsv,
                     bsw, wsao);
  hipLaunchKernelGGL(k_proj, dim3(1024), dim3(256), 0, stream, wsao, wpj, pjb, out);
}

// Round 5
// 258.631 us; speedup vs baseline: 2.0481x; 1.0464x over previous
//
#include <hip/hip_runtime.h>

typedef __bf16 bf16;
typedef __bf16 bf16x8 __attribute__((ext_vector_type(8)));
typedef __bf16 bf16x4 __attribute__((ext_vector_type(4)));
typedef float f32x4 __attribute__((ext_vector_type(4)));
typedef float f32x16 __attribute__((ext_vector_type(16)));
typedef unsigned int u32;
typedef unsigned int u32x4 __attribute__((ext_vector_type(4)));

#define MFMA16(a, b, c) __builtin_amdgcn_mfma_f32_16x16x32_bf16(a, b, c, 0, 0, 0)
#define MFMA32(a, b, c) __builtin_amdgcn_mfma_f32_32x32x16_bf16(a, b, c, 0, 0, 0)

__device__ __forceinline__ u32 pack2(float a, float b) {
  unsigned short ua = __builtin_bit_cast(unsigned short, (bf16)a);
  unsigned short ub = __builtin_bit_cast(unsigned short, (bf16)b);
  return (u32)ua | ((u32)ub << 16);
}

// ---------------- fp32 -> bf16 weight convert ----------------
__global__ __launch_bounds__(256) void k_cvt(const float* __restrict__ src,
                                             bf16* __restrict__ dst, int n4) {
  int i = blockIdx.x * 256 + threadIdx.x;
  if (i < n4) {
    float4 v = ((const float4*)src)[i];
    bf16x4 o;
    o[0] = (bf16)v.x; o[1] = (bf16)v.y; o[2] = (bf16)v.z; o[3] = (bf16)v.w;
    ((bf16x4*)dst)[i] = o;
  }
}

// ---------------- dynamic position-bias MLP (961 rows) ----------------
__device__ __forceinline__ void lnrelu16(const float* in, float* out,
                                         const float* __restrict__ g,
                                         const float* __restrict__ b) {
  float mu = 0.f;
#pragma unroll
  for (int t = 0; t < 16; ++t) mu += in[t];
  mu *= 0.0625f;
  float var = 0.f;
#pragma unroll
  for (int t = 0; t < 16; ++t) { float d = in[t] - mu; var += d * d; }
  var *= 0.0625f;
  float inv = rsqrtf(var + 1e-5f);
#pragma unroll
  for (int t = 0; t < 16; ++t) {
    float v = (in[t] - mu) * inv * g[t] + b[t];
    out[t] = fmaxf(v, 0.f);
  }
}

__global__ __launch_bounds__(256) void k_dpb(
    const float* __restrict__ ppw, const float* __restrict__ ppb,
    const float* __restrict__ g1, const float* __restrict__ b1,
    const float* __restrict__ f1w, const float* __restrict__ f1b,
    const float* __restrict__ g2, const float* __restrict__ b2,
    const float* __restrict__ f2w, const float* __restrict__ f2b,
    const float* __restrict__ g3, const float* __restrict__ b3,
    const float* __restrict__ f3w, const float* __restrict__ f3b,
    float* __restrict__ ptab) {
  int l = blockIdx.x * 256 + threadIdx.x;
  if (l >= 961) return;
  float dh = (float)(l / 31) - 15.f;
  float dw = (float)(l % 31) - 15.f;
  float p[16], a[16], y[16];
#pragma unroll
  for (int t = 0; t < 16; ++t) p[t] = dh * ppw[2 * t] + dw * ppw[2 * t + 1] + ppb[t];
  lnrelu16(p, a, g1, b1);
#pragma unroll
  for (int t = 0; t < 16; ++t) {
    float s = f1b[t];
#pragma unroll
    for (int u = 0; u < 16; ++u) s += a[u] * f1w[t * 16 + u];
    y[t] = s;
  }
  lnrelu16(y, a, g2, b2);
#pragma unroll
  for (int t = 0; t < 16; ++t) {
    float s = f2b[t];
#pragma unroll
    for (int u = 0; u < 16; ++u) s += a[u] * f2w[t * 16 + u];
    p[t] = s;
  }
  lnrelu16(p, a, g3, b3);
#pragma unroll
  for (int t = 0; t < 8; ++t) {
    float s = f3b[t];
#pragma unroll
    for (int u = 0; u < 16; ++u) s += a[u] * f3w[t * 16 + u];
    ptab[l * 8 + t] = s;
  }
}

// ---------------- bias table in 32x32 MFMA D-fragment order ----------------
// Bsw[tg=(h*8+qt)*8+kt2][lane][reg] = rpb[h][n=qt*32+(lane&31)]
//                                        [key=kt2*32+(reg&3)+8*(reg>>2)+4*(lane>>5)]
__global__ __launch_bounds__(256) void k_bias(const float* __restrict__ ptab,
                                              bf16* __restrict__ Bsw) {
  int idx = blockIdx.x * 256 + threadIdx.x;  // 128 blocks -> 32768 threads
  int lane = idx & 63, tg = idx >> 6;        // tg 0..511
  int h = tg >> 6, qt = (tg >> 3) & 7, kt2 = tg & 7;
  int l31 = lane & 31, hi2 = lane >> 5;
  int n = qt * 32 + l31;
  int i1 = n >> 4, j1 = n & 15;
  bf16x8 o0, o1;
#pragma unroll
  for (int reg = 0; reg < 16; ++reg) {
    int key = kt2 * 32 + (reg & 3) + 8 * (reg >> 2) + 4 * hi2;
    int i2 = key >> 4, j2 = key & 15;
    int li = (i1 - i2 + 15) * 31 + (j1 - j2 + 15);
    bf16 v = (bf16)ptab[li * 8 + h];
    if (reg < 8) o0[reg] = v; else o1[reg - 8] = v;
  }
  bf16* dst = Bsw + tg * 1024 + lane * 16;
  *(bf16x8*)dst = o0;
  *(bf16x8*)(dst + 8) = o1;
}

// ---------------- qkv GEMM: (B*N,256) x (768,256)^T ----------------
// 512-thread blocks, 8 waves. x-slice staged through LDS with coalesced
// float4 loads (replaces the 128-scalar-load gather that was latency-bound).
__global__ __launch_bounds__(512) void k_qkv(
    const float* __restrict__ x, const bf16* __restrict__ Wb,
    const float* __restrict__ qb, bf16* __restrict__ q, bf16* __restrict__ kk,
    bf16* __restrict__ vT) {
  __shared__ bf16 Al[128 * 264];   // 67,584 B: x^T slice [n_local][c], pad 264
  __shared__ bf16 Vb[8][16 * 36];  // 9,216 B: per-wave v transpose bounce
  const int b = blockIdx.x >> 1;
  const int nh = blockIdx.x & 1;
  const int tid = threadIdx.x;
  const int lane = tid & 63;
  const int wave = tid >> 6;
  const int wn = wave & 3, oh = wave >> 2;
  const int l15 = lane & 15, l4 = lane >> 4;
  const int n0 = nh * 128 + wn * 32;

  // ---- stage x[b][c][nh*128 .. +128) into Al[n_local][c] (bf16) ----
  const float* xb = x + b * 65536 + nh * 128;
#pragma unroll
  for (int it = 0; it < 16; ++it) {
    int f = tid + it * 512;          // float4 id: c = f>>5, n_local = (f&31)*4
    int c = f >> 5, nl = (f & 31) * 4;
    float4 v = *(const float4*)(xb + c * 256 + nl);
    Al[nl * 264 + c] = (bf16)v.x;
    Al[(nl + 1) * 264 + c] = (bf16)v.y;
    Al[(nl + 2) * 264 + c] = (bf16)v.z;
    Al[(nl + 3) * 264 + c] = (bf16)v.w;
  }
  __syncthreads();

  // ---- A-fragments once from LDS ----
  bf16x8 af[2][8];  // [n-tile][k-step], A row = l15 (=n), k = l4*8+j (=c)
#pragma unroll
  for (int nt = 0; nt < 2; ++nt)
#pragma unroll
    for (int kc = 0; kc < 8; ++kc)
      af[nt][kc] =
          *(const bf16x8*)(Al + (wn * 32 + nt * 16 + l15) * 264 + kc * 32 + l4 * 8);

  const f32x4 fz = {0.f, 0.f, 0.f, 0.f};
  bf16* lb = Vb[wave];
  for (int ot = oh * 24; ot < oh * 24 + 24; ++ot) {
    int o = ot * 16 + l15;  // B col = l15
    f32x4 acc0 = fz, acc1 = fz;
    const bf16* wr = Wb + o * 256 + l4 * 8;
#pragma unroll
    for (int kc = 0; kc < 8; ++kc) {
      bf16x8 bfr = *(const bf16x8*)(wr + kc * 32);
      acc0 = MFMA16(af[0][kc], bfr, acc0);
      acc1 = MFMA16(af[1][kc], bfr, acc1);
    }
    // D: row n = (l4*4 + r), col o = l15
    float bias = qb[o];
    int seg = o >> 8;
    int h = (o >> 5) & 7;
    int d = o & 31;
    int base = (b * 8 + h) * 8192;
    if (seg == 0) {
      bf16* dq = q + base + d;
#pragma unroll
      for (int nt = 0; nt < 2; ++nt)
#pragma unroll
        for (int r = 0; r < 4; ++r) {
          int n = n0 + nt * 16 + l4 * 4 + r;
          float v = nt ? acc1[r] : acc0[r];
          dq[n * 32] = (bf16)((v + bias) * 0.17677669529663687f);
        }
    } else if (seg == 1) {
      bf16* dk = kk + base + d;
#pragma unroll
      for (int nt = 0; nt < 2; ++nt)
#pragma unroll
        for (int r = 0; r < 4; ++r) {
          int n = n0 + nt * 16 + l4 * 4 + r;
          float v = nt ? acc1[r] : acc0[r];
          dk[n * 32] = (bf16)(v + bias);
        }
    } else {
      // v: transpose 16d x 32n tile through LDS -> contiguous-n 64B rows
#pragma unroll
      for (int nt = 0; nt < 2; ++nt) {
        f32x4 a = nt ? acc1 : acc0;
        *(u32*)(lb + l15 * 36 + nt * 16 + l4 * 4) = pack2(a[0] + bias, a[1] + bias);
        *(u32*)(lb + l15 * 36 + nt * 16 + l4 * 4 + 2) = pack2(a[2] + bias, a[3] + bias);
      }
      asm volatile("s_waitcnt lgkmcnt(0)" ::: "memory");
      __builtin_amdgcn_sched_barrier(0);
      int dl = lane >> 2, chv = lane & 3;
      bf16x4 rv0 = *(bf16x4*)(lb + dl * 36 + chv * 8);
      bf16x4 rv1 = *(bf16x4*)(lb + dl * 36 + chv * 8 + 4);
      asm volatile("s_waitcnt lgkmcnt(0)" ::: "memory");
      __builtin_amdgcn_sched_barrier(0);
      int d2 = (ot & 1) * 16 + dl;
      bf16* dv2 = vT + base + d2 * 256 + n0 + chv * 8;
      *(bf16x4*)dv2 = rv0;
      *(bf16x4*)(dv2 + 4) = rv1;
    }
  }
}

// ---------------- attention per (b, h): 32x32 swapped-operand scheme ----------------
// S^T = K·Q (MFMA 32x32x16): lane owns softmax column n in registers.
// PV B-frags built in-register via one half-wave swap per 16-key block.
__global__ __launch_bounds__(256, 2) void k_attn(
    const bf16* __restrict__ q, const bf16* __restrict__ kk,
    const bf16* __restrict__ vT, const bf16* __restrict__ Bsw,
    bf16* __restrict__ ao) {
  __shared__ bf16 Kl[256 * 36];    // 18,432 B
  __shared__ bf16 Ob[4][32 * 36];  // 9,216 B: per-wave output transpose bounce
  const int bh = blockIdx.x;
  const int b = bh >> 3, h = bh & 7;
  const int tid = threadIdx.x;
  const int lane = tid & 63, wave = tid >> 6;
  const int l31 = lane & 31, hi = lane >> 5;

  const bf16* Kg = kk + bh * 8192;
#pragma unroll
  for (int i = 0; i < 4; ++i) {
    int t = tid + i * 256;
    int n = t >> 2, dc = t & 3;
    *(bf16x8*)(Kl + n * 36 + dc * 8) = *(const bf16x8*)(Kg + n * 32 + dc * 8);
  }
  __syncthreads();

  const bf16* Vg = vT + bh * 8192;
  bf16* ob = Ob[wave];
  for (int qi = 0; qi < 2; ++qi) {
    const int qt = wave * 2 + qi, q0 = qt * 32;
    // Q B-frags: col = l31 = n, k = c = cs*16 + hi*8 + j
    bf16x8 qf0 = *(const bf16x8*)(q + bh * 8192 + (q0 + l31) * 32 + hi * 8);
    bf16x8 qf1 = *(const bf16x8*)(q + bh * 8192 + (q0 + l31) * 32 + 16 + hi * 8);
    const bf16* bq = Bsw + (h * 8 + qt) * 8192 + lane * 16;
    f32x16 s[8];
#pragma unroll
    for (int kt2 = 0; kt2 < 8; ++kt2) {
      bf16x8 ba = *(const bf16x8*)(bq + kt2 * 1024);
      bf16x8 bbv = *(const bf16x8*)(bq + kt2 * 1024 + 8);
      f32x16 acc;
#pragma unroll
      for (int i = 0; i < 8; ++i) {
        acc[i] = (float)ba[i];
        acc[8 + i] = (float)bbv[i];
      }
      // A-frag K: row = l31 = key_local, k = c
      bf16x8 kf0 = *(const bf16x8*)(Kl + (kt2 * 32 + l31) * 36 + hi * 8);
      bf16x8 kf1 = *(const bf16x8*)(Kl + (kt2 * 32 + l31) * 36 + 16 + hi * 8);
      acc = MFMA32(kf0, qf0, acc);
      acc = MFMA32(kf1, qf1, acc);
      s[kt2] = acc;  // S^T[key=kt2*32+(reg&3)+8*(reg>>2)+4*hi][n=q0+l31]
    }
    // softmax over the column (in-register + one half-wave swap)
    float m = -1e30f;
#pragma unroll
    for (int kt2 = 0; kt2 < 8; ++kt2)
#pragma unroll
      for (int i = 0; i < 16; ++i) m = fmaxf(m, s[kt2][i]);
    m = fmaxf(m, __shfl_xor(m, 32));
    float sum = 0.f;
#pragma unroll
    for (int kt2 = 0; kt2 < 8; ++kt2)
#pragma unroll
      for (int i = 0; i < 16; ++i) {
        float e = __expf(s[kt2][i] - m);
        s[kt2][i] = e;
        sum += e;
      }
    sum += __shfl_xor(sum, 32);
    const float inv = 1.f / sum;

    f32x16 o;
#pragma unroll
    for (int i = 0; i < 16; ++i) o[i] = 0.f;
#pragma unroll
    for (int kt2 = 0; kt2 < 8; ++kt2) {
      u32 lo[4], hw[4];
#pragma unroll
      for (int qq = 0; qq < 4; ++qq) {
        lo[qq] = pack2(s[kt2][4 * qq] * inv, s[kt2][4 * qq + 1] * inv);
        hw[qq] = pack2(s[kt2][4 * qq + 2] * inv, s[kt2][4 * qq + 3] * inv);
      }
#pragma unroll
      for (int sb = 0; sb < 2; ++sb) {
        // lane quad q=2sb+hi holds keys [16sb+8hi, +4); partner holds the rest
        u32 keep_lo = hi ? lo[2 * sb + 1] : lo[2 * sb];
        u32 keep_hi = hi ? hw[2 * sb + 1] : hw[2 * sb];
        u32 send_lo = hi ? lo[2 * sb] : lo[2 * sb + 1];
        u32 send_hi = hi ? hw[2 * sb] : hw[2 * sb + 1];
        u32 rlo = __shfl_xor(send_lo, 32);
        u32 rhi = __shfl_xor(send_hi, 32);
        u32x4 bw;
        bw[0] = hi ? rlo : keep_lo;
        bw[1] = hi ? rhi : keep_hi;
        bw[2] = hi ? keep_lo : rlo;
        bw[3] = hi ? keep_hi : rhi;
        bf16x8 pf = __builtin_bit_cast(bf16x8, bw);
        // V^T A-frag: row = l31 = d, k = key
        bf16x8 vf = *(const bf16x8*)(Vg + l31 * 256 + kt2 * 32 + sb * 16 + hi * 8);
        o = MFMA32(vf, pf, o);
      }
    }
    // O^T[d][n] -> transpose via per-wave LDS -> 64B-contiguous ao rows
#pragma unroll
    for (int qq = 0; qq < 4; ++qq) {
      *(u32*)(ob + l31 * 36 + 8 * qq + 4 * hi) = pack2(o[4 * qq], o[4 * qq + 1]);
      *(u32*)(ob + l31 * 36 + 8 * qq + 4 * hi + 2) = pack2(o[4 * qq + 2], o[4 * qq + 3]);
    }
    asm volatile("s_waitcnt lgkmcnt(0)" ::: "memory");
    __builtin_amdgcn_sched_barrier(0);
    int n2 = lane >> 1, ch = lane & 1;
    bf16x4 r0 = *(bf16x4*)(ob + n2 * 36 + ch * 16);
    bf16x4 r1 = *(bf16x4*)(ob + n2 * 36 + ch * 16 + 4);
    bf16x4 r2 = *(bf16x4*)(ob + n2 * 36 + ch * 16 + 8);
    bf16x4 r3 = *(bf16x4*)(ob + n2 * 36 + ch * 16 + 12);
    asm volatile("s_waitcnt lgkmcnt(0)" ::: "memory");
    __builtin_amdgcn_sched_barrier(0);
    bf16* dst = ao + (b * 256 + q0 + n2) * 256 + h * 32 + ch * 16;
    *(bf16x4*)dst = r0;
    *(bf16x4*)(dst + 4) = r1;
    *(bf16x4*)(dst + 8) = r2;
    *(bf16x4*)(dst + 12) = r3;
  }
}

// ---------------- output projection, written transposed (b, o, n) ----------------
__global__ __launch_bounds__(256) void k_proj(
    const bf16* __restrict__ ao, const bf16* __restrict__ Wp,
    const float* __restrict__ pb, float* __restrict__ out) {
  const int i = blockIdx.x;
  const int flat = (i & 7) * 128 + (i >> 3);  // XCD-bijective swizzle
  const int b = flat >> 2, oc = flat & 3;
  const int lane = threadIdx.x & 63, wave = threadIdx.x >> 6;
  const int l15 = lane & 15, l4 = lane >> 4;
  const int otile = oc * 4 + wave;
  bf16x8 af[8];  // A = proj_w: row o = l15, k = c
  const bf16* wr = Wp + (otile * 16 + l15) * 256 + l4 * 8;
#pragma unroll
  for (int kc = 0; kc < 8; ++kc) af[kc] = *(const bf16x8*)(wr + kc * 32);
  float bias[4];
#pragma unroll
  for (int r = 0; r < 4; ++r) bias[r] = pb[otile * 16 + l4 * 4 + r];
  const bf16* aob = ao + b * 65536;
  float* outb = out + b * 65536 + otile * 16 * 256;
  const f32x4 fz = {0.f, 0.f, 0.f, 0.f};
  for (int nt = 0; nt < 16; ++nt) {
    f32x4 acc = fz;
#pragma unroll
    for (int kc = 0; kc < 8; ++kc) {
      bf16x8 bfr = *(const bf16x8*)(aob + (nt * 16 + l15) * 256 + kc * 32 + l4 * 8);
      acc = MFMA16(af[kc], bfr, acc);
    }
#pragma unroll
    for (int r = 0; r < 4; ++r)
      outb[(l4 * 4 + r) * 256 + nt * 16 + l15] = acc[r] + bias[r];
  }
}

extern "C" void kernel_launch(void* const* d_in, const int* in_sizes, int n_in,
                              void* d_out, int out_size, void* d_ws, size_t ws_size,
                              hipStream_t stream) {
  const float* x    = (const float*)d_in[0];
  const float* qkvw = (const float*)d_in[1];
  const float* qkvb = (const float*)d_in[2];
  const float* pjw  = (const float*)d_in[3];
  const float* pjb  = (const float*)d_in[4];
  const float* ppw  = (const float*)d_in[5];
  const float* ppb  = (const float*)d_in[6];
  const float* g1 = (const float*)d_in[7];   const float* b1 = (const float*)d_in[8];
  const float* f1w = (const float*)d_in[9];  const float* f1b = (const float*)d_in[10];
  const float* g2 = (const float*)d_in[11];  const float* b2 = (const float*)d_in[12];
  const float* f2w = (const float*)d_in[13]; const float* f2b = (const float*)d_in[14];
  const float* g3 = (const float*)d_in[15];  const float* b3 = (const float*)d_in[16];
  const float* f3w = (const float*)d_in[17]; const float* f3b = (const float*)d_in[18];
  float* out = (float*)d_out;

  // ws: q | k | vT | ao (16,777,216 bf16 each) | ptab 8192 f32 | Wqkv 196608 bf16
  //     | Wproj 65536 bf16 | Bsw 524288 bf16
  bf16* wsq  = (bf16*)d_ws;
  bf16* wsk  = wsq + 16777216;
  bf16* wsv  = wsk + 16777216;
  bf16* wsao = wsv + 16777216;
  float* ptab = (float*)(wsao + 16777216);
  bf16* wqkv = (bf16*)(ptab + 8192);
  bf16* wpj  = wqkv + 196608;
  bf16* bsw  = wpj + 65536;

  hipLaunchKernelGGL(k_cvt, dim3(192), dim3(256), 0, stream, qkvw, wqkv, 49152);
  hipLaunchKernelGGL(k_cvt, dim3(64), dim3(256), 0, stream, pjw, wpj, 16384);
  hipLaunchKernelGGL(k_dpb, dim3(4), dim3(256), 0, stream, ppw, ppb, g1, b1, f1w,
                     f1b, g2, b2, f2w, f2b, g3, b3, f3w, f3b, ptab);
  hipLaunchKernelGGL(k_bias, dim3(128), dim3(256), 0, stream, ptab, bsw);
  hipLaunchKernelGGL(k_qkv, dim3(512), dim3(512), 0, stream, x, wqkv, qkvb, wsq,
                     wsk, wsv);
  hipLaunchKernelGGL(k_attn, dim3(2048), dim3(256), 0, stream, wsq, wsk, wsv,
                     bsw, wsao);
  hipLaunchKernelGGL(k_proj, dim3(1024), dim3(256), 0, stream, wsao, wpj, pjb, out);
}

// Round 6
// 235.022 us; speedup vs baseline: 2.2539x; 1.1005x over previous
//
#include <hip/hip_runtime.h>

typedef __bf16 bf16;
typedef __bf16 bf16x8 __attribute__((ext_vector_type(8)));
typedef __bf16 bf16x4 __attribute__((ext_vector_type(4)));
typedef float f32x4 __attribute__((ext_vector_type(4)));
typedef float f32x16 __attribute__((ext_vector_type(16)));
typedef unsigned int u32;
typedef unsigned int u32x4 __attribute__((ext_vector_type(4)));

#define MFMA16(a, b, c) __builtin_amdgcn_mfma_f32_16x16x32_bf16(a, b, c, 0, 0, 0)
#define MFMA32(a, b, c) __builtin_amdgcn_mfma_f32_32x32x16_bf16(a, b, c, 0, 0, 0)

__device__ __forceinline__ u32 pack2(float a, float b) {
  unsigned short ua = __builtin_bit_cast(unsigned short, (bf16)a);
  unsigned short ub = __builtin_bit_cast(unsigned short, (bf16)b);
  return (u32)ua | ((u32)ub << 16);
}

// ---------------- fp32 -> bf16 weight convert ----------------
__global__ __launch_bounds__(256) void k_cvt(const float* __restrict__ src,
                                             bf16* __restrict__ dst, int n4) {
  int i = blockIdx.x * 256 + threadIdx.x;
  if (i < n4) {
    float4 v = ((const float4*)src)[i];
    bf16x4 o;
    o[0] = (bf16)v.x; o[1] = (bf16)v.y; o[2] = (bf16)v.z; o[3] = (bf16)v.w;
    ((bf16x4*)dst)[i] = o;
  }
}

// ---------------- dynamic position-bias MLP (961 rows) ----------------
__device__ __forceinline__ void lnrelu16(const float* in, float* out,
                                         const float* __restrict__ g,
                                         const float* __restrict__ b) {
  float mu = 0.f;
#pragma unroll
  for (int t = 0; t < 16; ++t) mu += in[t];
  mu *= 0.0625f;
  float var = 0.f;
#pragma unroll
  for (int t = 0; t < 16; ++t) { float d = in[t] - mu; var += d * d; }
  var *= 0.0625f;
  float inv = rsqrtf(var + 1e-5f);
#pragma unroll
  for (int t = 0; t < 16; ++t) {
    float v = (in[t] - mu) * inv * g[t] + b[t];
    out[t] = fmaxf(v, 0.f);
  }
}

__global__ __launch_bounds__(256) void k_dpb(
    const float* __restrict__ ppw, const float* __restrict__ ppb,
    const float* __restrict__ g1, const float* __restrict__ b1,
    const float* __restrict__ f1w, const float* __restrict__ f1b,
    const float* __restrict__ g2, const float* __restrict__ b2,
    const float* __restrict__ f2w, const float* __restrict__ f2b,
    const float* __restrict__ g3, const float* __restrict__ b3,
    const float* __restrict__ f3w, const float* __restrict__ f3b,
    float* __restrict__ ptab) {
  int l = blockIdx.x * 256 + threadIdx.x;
  if (l >= 961) return;
  float dh = (float)(l / 31) - 15.f;
  float dw = (float)(l % 31) - 15.f;
  float p[16], a[16], y[16];
#pragma unroll
  for (int t = 0; t < 16; ++t) p[t] = dh * ppw[2 * t] + dw * ppw[2 * t + 1] + ppb[t];
  lnrelu16(p, a, g1, b1);
#pragma unroll
  for (int t = 0; t < 16; ++t) {
    float s = f1b[t];
#pragma unroll
    for (int u = 0; u < 16; ++u) s += a[u] * f1w[t * 16 + u];
    y[t] = s;
  }
  lnrelu16(y, a, g2, b2);
#pragma unroll
  for (int t = 0; t < 16; ++t) {
    float s = f2b[t];
#pragma unroll
    for (int u = 0; u < 16; ++u) s += a[u] * f2w[t * 16 + u];
    p[t] = s;
  }
  lnrelu16(p, a, g3, b3);
#pragma unroll
  for (int t = 0; t < 8; ++t) {
    float s = f3b[t];
#pragma unroll
    for (int u = 0; u < 16; ++u) s += a[u] * f3w[t * 16 + u];
    ptab[l * 8 + t] = s;
  }
}

// ---------------- bias table in 32x32 MFMA D-fragment order ----------------
__global__ __launch_bounds__(256) void k_bias(const float* __restrict__ ptab,
                                              bf16* __restrict__ Bsw) {
  int idx = blockIdx.x * 256 + threadIdx.x;  // 128 blocks -> 32768 threads
  int lane = idx & 63, tg = idx >> 6;        // tg 0..511
  int h = tg >> 6, qt = (tg >> 3) & 7, kt2 = tg & 7;
  int l31 = lane & 31, hi2 = lane >> 5;
  int n = qt * 32 + l31;
  int i1 = n >> 4, j1 = n & 15;
  bf16x8 o0, o1;
#pragma unroll
  for (int reg = 0; reg < 16; ++reg) {
    int key = kt2 * 32 + (reg & 3) + 8 * (reg >> 2) + 4 * hi2;
    int i2 = key >> 4, j2 = key & 15;
    int li = (i1 - i2 + 15) * 31 + (j1 - j2 + 15);
    bf16 v = (bf16)ptab[li * 8 + h];
    if (reg < 8) o0[reg] = v; else o1[reg - 8] = v;
  }
  bf16* dst = Bsw + tg * 1024 + lane * 16;
  *(bf16x8*)dst = o0;
  *(bf16x8*)(dst + 8) = o1;
}

// ---------------- qkv GEMM: (B*N,256) x (768,256)^T ----------------
// 512 threads, 8 waves = 2(M-halves of 64 rows) x 4(N-quarters of 192 cols).
// Stage A once -> K-loop accumulate (16 accs) -> batched epilogue per og.
__global__ __launch_bounds__(512) void k_qkv(
    const float* __restrict__ x, const bf16* __restrict__ Wb,
    const float* __restrict__ qb, bf16* __restrict__ q, bf16* __restrict__ kk,
    bf16* __restrict__ vT) {
  __shared__ bf16 Al[128 * 264];   // 67,584 B: x^T slice [n_local][c], pad 264
  __shared__ bf16 Vb[8][16 * 36];  // 9,216 B: per-wave v transpose bounce
  const int b = blockIdx.x >> 1;
  const int nh = blockIdx.x & 1;
  const int tid = threadIdx.x;
  const int lane = tid & 63;
  const int wave = tid >> 6;
  const int wm = wave & 1, wo = wave >> 1;
  const int l15 = lane & 15, l4 = lane >> 4;
  const int n0 = nh * 128 + wm * 64;

  // ---- stage x[b][c][nh*128 .. +128) into Al[n_local][c] (bf16) ----
  const float* xb = x + b * 65536 + nh * 128;
#pragma unroll
  for (int it = 0; it < 16; ++it) {
    int f = tid + it * 512;          // float4 id: c = f>>5, n_local = (f&31)*4
    int c = f >> 5, nl = (f & 31) * 4;
    float4 v = *(const float4*)(xb + c * 256 + nl);
    Al[nl * 264 + c] = (bf16)v.x;
    Al[(nl + 1) * 264 + c] = (bf16)v.y;
    Al[(nl + 2) * 264 + c] = (bf16)v.z;
    Al[(nl + 3) * 264 + c] = (bf16)v.w;
  }
  __syncthreads();

  const f32x4 fz = {0.f, 0.f, 0.f, 0.f};
  bf16* lb = Vb[wave];
  for (int og = 0; og < 3; ++og) {
    const int ot0 = wo * 12 + og * 4;
    f32x4 acc[4][4];  // [nt][oi]
#pragma unroll
    for (int nt = 0; nt < 4; ++nt)
#pragma unroll
      for (int oi = 0; oi < 4; ++oi) acc[nt][oi] = fz;
#pragma unroll
    for (int kc = 0; kc < 8; ++kc) {
      bf16x8 afr[4], bfr[4];
#pragma unroll
      for (int nt = 0; nt < 4; ++nt)
        afr[nt] = *(const bf16x8*)(Al + (wm * 64 + nt * 16 + l15) * 264 +
                                   kc * 32 + l4 * 8);
#pragma unroll
      for (int oi = 0; oi < 4; ++oi)
        bfr[oi] = *(const bf16x8*)(Wb + ((ot0 + oi) * 16 + l15) * 256 +
                                   kc * 32 + l4 * 8);
#pragma unroll
      for (int nt = 0; nt < 4; ++nt)
#pragma unroll
        for (int oi = 0; oi < 4; ++oi)
          acc[nt][oi] = MFMA16(afr[nt], bfr[oi], acc[nt][oi]);
    }
    // ---- batched epilogue for this 64x64 group ----
#pragma unroll
    for (int oi = 0; oi < 4; ++oi) {
      int ot = ot0 + oi;
      int o = ot * 16 + l15;  // B col = l15
      float bias = qb[o];
      int seg = o >> 8;
      int h = (o >> 5) & 7;
      int d = o & 31;
      int base = (b * 8 + h) * 8192;
#pragma unroll
      for (int pr = 0; pr < 2; ++pr) {
        f32x4 acc0 = acc[2 * pr][oi], acc1 = acc[2 * pr + 1][oi];
        int n0p = n0 + pr * 32;
        if (seg == 0) {
          bf16* dq = q + base + d;
#pragma unroll
          for (int nt = 0; nt < 2; ++nt)
#pragma unroll
            for (int r = 0; r < 4; ++r) {
              int n = n0p + nt * 16 + l4 * 4 + r;
              float v = nt ? acc1[r] : acc0[r];
              dq[n * 32] = (bf16)((v + bias) * 0.17677669529663687f);
            }
        } else if (seg == 1) {
          bf16* dk = kk + base + d;
#pragma unroll
          for (int nt = 0; nt < 2; ++nt)
#pragma unroll
            for (int r = 0; r < 4; ++r) {
              int n = n0p + nt * 16 + l4 * 4 + r;
              float v = nt ? acc1[r] : acc0[r];
              dk[n * 32] = (bf16)(v + bias);
            }
        } else {
          // v: transpose 16d x 32n tile through LDS -> contiguous-n 64B rows
#pragma unroll
          for (int nt = 0; nt < 2; ++nt) {
            f32x4 a = nt ? acc1 : acc0;
            *(u32*)(lb + l15 * 36 + nt * 16 + l4 * 4) =
                pack2(a[0] + bias, a[1] + bias);
            *(u32*)(lb + l15 * 36 + nt * 16 + l4 * 4 + 2) =
                pack2(a[2] + bias, a[3] + bias);
          }
          asm volatile("s_waitcnt lgkmcnt(0)" ::: "memory");
          __builtin_amdgcn_sched_barrier(0);
          int dl = lane >> 2, chv = lane & 3;
          bf16x4 rv0 = *(bf16x4*)(lb + dl * 36 + chv * 8);
          bf16x4 rv1 = *(bf16x4*)(lb + dl * 36 + chv * 8 + 4);
          asm volatile("s_waitcnt lgkmcnt(0)" ::: "memory");
          __builtin_amdgcn_sched_barrier(0);
          int d2 = (ot & 1) * 16 + dl;
          bf16* dv2 = vT + base + d2 * 256 + n0p + chv * 8;
          *(bf16x4*)dv2 = rv0;
          *(bf16x4*)(dv2 + 4) = rv1;
        }
      }
    }
  }
}

// ---------------- attention per (b, h): 32x32 swapped-operand scheme ----------------
__global__ __launch_bounds__(256, 2) void k_attn(
    const bf16* __restrict__ q, const bf16* __restrict__ kk,
    const bf16* __restrict__ vT, const bf16* __restrict__ Bsw,
    bf16* __restrict__ ao) {
  __shared__ bf16 Kl[256 * 36];    // 18,432 B
  __shared__ bf16 Ob[4][32 * 36];  // 9,216 B: per-wave output transpose bounce
  const int bh = blockIdx.x;
  const int b = bh >> 3, h = bh & 7;
  const int tid = threadIdx.x;
  const int lane = tid & 63, wave = tid >> 6;
  const int l31 = lane & 31, hi = lane >> 5;

  const bf16* Kg = kk + bh * 8192;
#pragma unroll
  for (int i = 0; i < 4; ++i) {
    int t = tid + i * 256;
    int n = t >> 2, dc = t & 3;
    *(bf16x8*)(Kl + n * 36 + dc * 8) = *(const bf16x8*)(Kg + n * 32 + dc * 8);
  }
  __syncthreads();

  const bf16* Vg = vT + bh * 8192;
  bf16* ob = Ob[wave];
  for (int qi = 0; qi < 2; ++qi) {
    const int qt = wave * 2 + qi, q0 = qt * 32;
    bf16x8 qf0 = *(const bf16x8*)(q + bh * 8192 + (q0 + l31) * 32 + hi * 8);
    bf16x8 qf1 = *(const bf16x8*)(q + bh * 8192 + (q0 + l31) * 32 + 16 + hi * 8);
    const bf16* bq = Bsw + (h * 8 + qt) * 8192 + lane * 16;
    f32x16 s[8];
#pragma unroll
    for (int kt2 = 0; kt2 < 8; ++kt2) {
      bf16x8 ba = *(const bf16x8*)(bq + kt2 * 1024);
      bf16x8 bbv = *(const bf16x8*)(bq + kt2 * 1024 + 8);
      f32x16 acc;
#pragma unroll
      for (int i = 0; i < 8; ++i) {
        acc[i] = (float)ba[i];
        acc[8 + i] = (float)bbv[i];
      }
      bf16x8 kf0 = *(const bf16x8*)(Kl + (kt2 * 32 + l31) * 36 + hi * 8);
      bf16x8 kf1 = *(const bf16x8*)(Kl + (kt2 * 32 + l31) * 36 + 16 + hi * 8);
      acc = MFMA32(kf0, qf0, acc);
      acc = MFMA32(kf1, qf1, acc);
      s[kt2] = acc;  // S^T[key=kt2*32+(reg&3)+8*(reg>>2)+4*hi][n=q0+l31]
    }
    float m = -1e30f;
#pragma unroll
    for (int kt2 = 0; kt2 < 8; ++kt2)
#pragma unroll
      for (int i = 0; i < 16; ++i) m = fmaxf(m, s[kt2][i]);
    m = fmaxf(m, __shfl_xor(m, 32));
    float sum = 0.f;
#pragma unroll
    for (int kt2 = 0; kt2 < 8; ++kt2)
#pragma unroll
      for (int i = 0; i < 16; ++i) {
        float e = __expf(s[kt2][i] - m);
        s[kt2][i] = e;
        sum += e;
      }
    sum += __shfl_xor(sum, 32);
    const float inv = 1.f / sum;

    f32x16 o;
#pragma unroll
    for (int i = 0; i < 16; ++i) o[i] = 0.f;
#pragma unroll
    for (int kt2 = 0; kt2 < 8; ++kt2) {
      u32 lo[4], hw[4];
#pragma unroll
      for (int qq = 0; qq < 4; ++qq) {
        lo[qq] = pack2(s[kt2][4 * qq] * inv, s[kt2][4 * qq + 1] * inv);
        hw[qq] = pack2(s[kt2][4 * qq + 2] * inv, s[kt2][4 * qq + 3] * inv);
      }
#pragma unroll
      for (int sb = 0; sb < 2; ++sb) {
        u32 keep_lo = hi ? lo[2 * sb + 1] : lo[2 * sb];
        u32 keep_hi = hi ? hw[2 * sb + 1] : hw[2 * sb];
        u32 send_lo = hi ? lo[2 * sb] : lo[2 * sb + 1];
        u32 send_hi = hi ? hw[2 * sb] : hw[2 * sb + 1];
        u32 rlo = __shfl_xor(send_lo, 32);
        u32 rhi = __shfl_xor(send_hi, 32);
        u32x4 bw;
        bw[0] = hi ? rlo : keep_lo;
        bw[1] = hi ? rhi : keep_hi;
        bw[2] = hi ? keep_lo : rlo;
        bw[3] = hi ? keep_hi : rhi;
        bf16x8 pf = __builtin_bit_cast(bf16x8, bw);
        bf16x8 vf = *(const bf16x8*)(Vg + l31 * 256 + kt2 * 32 + sb * 16 + hi * 8);
        o = MFMA32(vf, pf, o);
      }
    }
#pragma unroll
    for (int qq = 0; qq < 4; ++qq) {
      *(u32*)(ob + l31 * 36 + 8 * qq + 4 * hi) = pack2(o[4 * qq], o[4 * qq + 1]);
      *(u32*)(ob + l31 * 36 + 8 * qq + 4 * hi + 2) = pack2(o[4 * qq + 2], o[4 * qq + 3]);
    }
    asm volatile("s_waitcnt lgkmcnt(0)" ::: "memory");
    __builtin_amdgcn_sched_barrier(0);
    int n2 = lane >> 1, ch = lane & 1;
    bf16x4 r0 = *(bf16x4*)(ob + n2 * 36 + ch * 16);
    bf16x4 r1 = *(bf16x4*)(ob + n2 * 36 + ch * 16 + 4);
    bf16x4 r2 = *(bf16x4*)(ob + n2 * 36 + ch * 16 + 8);
    bf16x4 r3 = *(bf16x4*)(ob + n2 * 36 + ch * 16 + 12);
    asm volatile("s_waitcnt lgkmcnt(0)" ::: "memory");
    __builtin_amdgcn_sched_barrier(0);
    bf16* dst = ao + (b * 256 + q0 + n2) * 256 + h * 32 + ch * 16;
    *(bf16x4*)dst = r0;
    *(bf16x4*)(dst + 4) = r1;
    *(bf16x4*)(dst + 8) = r2;
    *(bf16x4*)(dst + 12) = r3;
  }
}

// ---------------- output projection, written transposed (b, o, n) ----------------
__global__ __launch_bounds__(256) void k_proj(
    const bf16* __restrict__ ao, const bf16* __restrict__ Wp,
    const float* __restrict__ pb, float* __restrict__ out) {
  const int i = blockIdx.x;
  const int flat = (i & 7) * 128 + (i >> 3);  // XCD-bijective swizzle
  const int b = flat >> 2, oc = flat & 3;
  const int lane = threadIdx.x & 63, wave = threadIdx.x >> 6;
  const int l15 = lane & 15, l4 = lane >> 4;
  const int otile = oc * 4 + wave;
  bf16x8 af[8];  // A = proj_w: row o = l15, k = c
  const bf16* wr = Wp + (otile * 16 + l15) * 256 + l4 * 8;
#pragma unroll
  for (int kc = 0; kc < 8; ++kc) af[kc] = *(const bf16x8*)(wr + kc * 32);
  float bias[4];
#pragma unroll
  for (int r = 0; r < 4; ++r) bias[r] = pb[otile * 16 + l4 * 4 + r];
  const bf16* aob = ao + b * 65536;
  float* outb = out + b * 65536 + otile * 16 * 256;
  const f32x4 fz = {0.f, 0.f, 0.f, 0.f};
  for (int nt = 0; nt < 16; ++nt) {
    f32x4 acc = fz;
#pragma unroll
    for (int kc = 0; kc < 8; ++kc) {
      bf16x8 bfr = *(const bf16x8*)(aob + (nt * 16 + l15) * 256 + kc * 32 + l4 * 8);
      acc = MFMA16(af[kc], bfr, acc);
    }
#pragma unroll
    for (int r = 0; r < 4; ++r)
      outb[(l4 * 4 + r) * 256 + nt * 16 + l15] = acc[r] + bias[r];
  }
}

extern "C" void kernel_launch(void* const* d_in, const int* in_sizes, int n_in,
                              void* d_out, int out_size, void* d_ws, size_t ws_size,
                              hipStream_t stream) {
  const float* x    = (const float*)d_in[0];
  const float* qkvw = (const float*)d_in[1];
  const float* qkvb = (const float*)d_in[2];
  const float* pjw  = (const float*)d_in[3];
  const float* pjb  = (const float*)d_in[4];
  const float* ppw  = (const float*)d_in[5];
  const float* ppb  = (const float*)d_in[6];
  const float* g1 = (const float*)d_in[7];   const float* b1 = (const float*)d_in[8];
  const float* f1w = (const float*)d_in[9];  const float* f1b = (const float*)d_in[10];
  const float* g2 = (const float*)d_in[11];  const float* b2 = (const float*)d_in[12];
  const float* f2w = (const float*)d_in[13]; const float* f2b = (const float*)d_in[14];
  const float* g3 = (const float*)d_in[15];  const float* b3 = (const float*)d_in[16];
  const float* f3w = (const float*)d_in[17]; const float* f3b = (const float*)d_in[18];
  float* out = (float*)d_out;

  // ws: q | k | vT | ao (16,777,216 bf16 each) | ptab 8192 f32 | Wqkv 196608 bf16
  //     | Wproj 65536 bf16 | Bsw 524288 bf16
  bf16* wsq  = (bf16*)d_ws;
  bf16* wsk  = wsq + 16777216;
  bf16* wsv  = wsk + 16777216;
  bf16* wsao = wsv + 16777216;
  float* ptab = (float*)(wsao + 16777216);
  bf16* wqkv = (bf16*)(ptab + 8192);
  bf16* wpj  = wqkv + 196608;
  bf16* bsw  = wpj + 65536;

  hipLaunchKernelGGL(k_cvt, dim3(192), dim3(256), 0, stream, qkvw, wqkv, 49152);
  hipLaunchKernelGGL(k_cvt, dim3(64), dim3(256), 0, stream, pjw, wpj, 16384);
  hipLaunchKernelGGL(k_dpb, dim3(4), dim3(256), 0, stream, ppw, ppb, g1, b1, f1w,
                     f1b, g2, b2, f2w, f2b, g3, b3, f3w, f3b, ptab);
  hipLaunchKernelGGL(k_bias, dim3(128), dim3(256), 0, stream, ptab, bsw);
  hipLaunchKernelGGL(k_qkv, dim3(512), dim3(512), 0, stream, x, wqkv, qkvb, wsq,
                     wsk, wsv);
  hipLaunchKernelGGL(k_attn, dim3(2048), dim3(256), 0, stream, wsq, wsk, wsv,
                     bsw, wsao);
  hipLaunchKernelGGL(k_proj, dim3(1024), dim3(256), 0, stream, wsao, wpj, pjb, out);
}

// Round 7
// 211.277 us; speedup vs baseline: 2.5072x; 1.1124x over previous
//
#include <hip/hip_runtime.h>

typedef __bf16 bf16;
typedef __bf16 bf16x8 __attribute__((ext_vector_type(8)));
typedef __bf16 bf16x4 __attribute__((ext_vector_type(4)));
typedef float f32x4 __attribute__((ext_vector_type(4)));
typedef float f32x16 __attribute__((ext_vector_type(16)));
typedef unsigned int u32;
typedef unsigned int u32x2 __attribute__((ext_vector_type(2)));
typedef unsigned int u32x4 __attribute__((ext_vector_type(4)));

#define MFMA16(a, b, c) __builtin_amdgcn_mfma_f32_16x16x32_bf16(a, b, c, 0, 0, 0)
#define MFMA32(a, b, c) __builtin_amdgcn_mfma_f32_32x32x16_bf16(a, b, c, 0, 0, 0)

__device__ __forceinline__ u32 pack2(float a, float b) {
  unsigned short ua = __builtin_bit_cast(unsigned short, (bf16)a);
  unsigned short ub = __builtin_bit_cast(unsigned short, (bf16)b);
  return (u32)ua | ((u32)ub << 16);
}

// ---------------- fp32 -> bf16 weight convert (proj_w) ----------------
__global__ __launch_bounds__(256) void k_cvt(const float* __restrict__ src,
                                             bf16* __restrict__ dst, int n4) {
  int i = blockIdx.x * 256 + threadIdx.x;
  if (i < n4) {
    float4 v = ((const float4*)src)[i];
    bf16x4 o;
    o[0] = (bf16)v.x; o[1] = (bf16)v.y; o[2] = (bf16)v.z; o[3] = (bf16)v.w;
    ((bf16x4*)dst)[i] = o;
  }
}

// ---------------- qkv_w -> B-fragment-major pack ----------------
// Wf[(ot*8+kc)*64+lane][8]: value = W[o=ot*16+(lane&15)][c=kc*32+(lane>>4)*8+j]
__global__ __launch_bounds__(256) void k_wpack(const float* __restrict__ w,
                                               bf16* __restrict__ dst) {
  int t = blockIdx.x * 256 + threadIdx.x;  // 96 blocks -> 24576 threads
  int lane = t & 63, fk = t >> 6;
  int ot = fk >> 3, kc = fk & 7;
  int o = ot * 16 + (lane & 15), cb = kc * 32 + (lane >> 4) * 8;
  const float* src = w + o * 256 + cb;
  bf16x8 v;
#pragma unroll
  for (int j = 0; j < 8; ++j) v[j] = (bf16)src[j];
  *(bf16x8*)(dst + (size_t)t * 8) = v;
}

// ---------------- dynamic position-bias MLP (961 rows) ----------------
__device__ __forceinline__ void lnrelu16(const float* in, float* out,
                                         const float* __restrict__ g,
                                         const float* __restrict__ b) {
  float mu = 0.f;
#pragma unroll
  for (int t = 0; t < 16; ++t) mu += in[t];
  mu *= 0.0625f;
  float var = 0.f;
#pragma unroll
  for (int t = 0; t < 16; ++t) { float d = in[t] - mu; var += d * d; }
  var *= 0.0625f;
  float inv = rsqrtf(var + 1e-5f);
#pragma unroll
  for (int t = 0; t < 16; ++t) {
    float v = (in[t] - mu) * inv * g[t] + b[t];
    out[t] = fmaxf(v, 0.f);
  }
}

__global__ __launch_bounds__(256) void k_dpb(
    const float* __restrict__ ppw, const float* __restrict__ ppb,
    const float* __restrict__ g1, const float* __restrict__ b1,
    const float* __restrict__ f1w, const float* __restrict__ f1b,
    const float* __restrict__ g2, const float* __restrict__ b2,
    const float* __restrict__ f2w, const float* __restrict__ f2b,
    const float* __restrict__ g3, const float* __restrict__ b3,
    const float* __restrict__ f3w, const float* __restrict__ f3b,
    float* __restrict__ ptab) {
  int l = blockIdx.x * 256 + threadIdx.x;
  if (l >= 961) return;
  float dh = (float)(l / 31) - 15.f;
  float dw = (float)(l % 31) - 15.f;
  float p[16], a[16], y[16];
#pragma unroll
  for (int t = 0; t < 16; ++t) p[t] = dh * ppw[2 * t] + dw * ppw[2 * t + 1] + ppb[t];
  lnrelu16(p, a, g1, b1);
#pragma unroll
  for (int t = 0; t < 16; ++t) {
    float s = f1b[t];
#pragma unroll
    for (int u = 0; u < 16; ++u) s += a[u] * f1w[t * 16 + u];
    y[t] = s;
  }
  lnrelu16(y, a, g2, b2);
#pragma unroll
  for (int t = 0; t < 16; ++t) {
    float s = f2b[t];
#pragma unroll
    for (int u = 0; u < 16; ++u) s += a[u] * f2w[t * 16 + u];
    p[t] = s;
  }
  lnrelu16(p, a, g3, b3);
#pragma unroll
  for (int t = 0; t < 8; ++t) {
    float s = f3b[t];
#pragma unroll
    for (int u = 0; u < 16; ++u) s += a[u] * f3w[t * 16 + u];
    ptab[l * 8 + t] = s;
  }
}

// ---------------- bias table in 32x32 MFMA D-fragment order ----------------
__global__ __launch_bounds__(256) void k_bias(const float* __restrict__ ptab,
                                              bf16* __restrict__ Bsw) {
  int idx = blockIdx.x * 256 + threadIdx.x;  // 128 blocks -> 32768 threads
  int lane = idx & 63, tg = idx >> 6;        // tg 0..511
  int h = tg >> 6, qt = (tg >> 3) & 7, kt2 = tg & 7;
  int l31 = lane & 31, hi2 = lane >> 5;
  int n = qt * 32 + l31;
  int i1 = n >> 4, j1 = n & 15;
  bf16x8 o0, o1;
#pragma unroll
  for (int reg = 0; reg < 16; ++reg) {
    int key = kt2 * 32 + (reg & 3) + 8 * (reg >> 2) + 4 * hi2;
    int i2 = key >> 4, j2 = key & 15;
    int li = (i1 - i2 + 15) * 31 + (j1 - j2 + 15);
    bf16 v = (bf16)ptab[li * 8 + h];
    if (reg < 8) o0[reg] = v; else o1[reg - 8] = v;
  }
  bf16* dst = Bsw + tg * 1024 + lane * 16;
  *(bf16x8*)dst = o0;
  *(bf16x8*)(dst + 8) = o1;
}

// ---------------- qkv GEMM: (B*N,256) x (768,256)^T ----------------
// 512 threads, 8 waves = 2(M-halves of 64 rows) x 4(N-quarters of 192 cols).
// Staging: quad-transpose in registers -> b64 writes into XOR-swizzled LDS
// (conflict-free b128 A-frag reads). W pre-packed fragment-major (coalesced).
__global__ __launch_bounds__(512) void k_qkv(
    const float* __restrict__ x, const bf16* __restrict__ Wf,
    const float* __restrict__ qb, bf16* __restrict__ q, bf16* __restrict__ kk,
    bf16* __restrict__ vT) {
  __shared__ bf16 Xl[128 * 256];   // 65,536 B, swizzled [n][c]
  __shared__ bf16 Vb[8][16 * 36];  // 9,216 B: per-wave v transpose bounce
  const int b = blockIdx.x >> 1;
  const int nh = blockIdx.x & 1;
  const int tid = threadIdx.x;
  const int lane = tid & 63;
  const int wave = tid >> 6;
  const int wm = wave & 1, wo = wave >> 1;
  const int l15 = lane & 15, l4 = lane >> 4;
  const int n0w = nh * 128 + wm * 64;

  // ---- stage x[b][c][nh*128+n] -> Xl[n][c] via quad transpose + swizzle ----
  {
    const float* xb = x + b * 65536 + nh * 128;
    const int p = tid & 3;
    const int Q = tid >> 2;
    const int n0 = (Q & 31) * 4;
    const int cgb = Q >> 5;  // 0..3
#pragma unroll
    for (int it = 0; it < 16; ++it) {
      const int c0 = (cgb + it * 4) * 4;
      float4 v = *(const float4*)(xb + (c0 + p) * 256 + n0);
      u32 u0 = pack2(v.x, v.y);   // (n0, n0+1) @ col c0+p
      u32 u1 = pack2(v.z, v.w);   // (n0+2, n0+3)
      u32 su0 = __shfl_xor(u0, 1);
      u32 su1 = __shfl_xor(u1, 1);
      u32 w, z;
      if (p & 1) {
        w = (su0 >> 16) | (u0 & 0xffff0000u);  // (c_ev,c_od) @ n0+1
        z = (su1 >> 16) | (u1 & 0xffff0000u);  // @ n0+3
      } else {
        w = (u0 & 0xffffu) | (su0 << 16);      // @ n0
        z = (u1 & 0xffffu) | (su1 << 16);      // @ n0+2
      }
      u32 sw = __shfl_xor(w, 2);
      u32 sz = __shfl_xor(z, 2);
      u32x2 o2;
      o2[0] = (p & 2) ? sz : w;   // (c0,c0+1) @ row n0+p
      o2[1] = (p & 2) ? z : sw;   // (c0+2,c0+3)
      const int n = n0 + p;
      const int wb = (2 * c0) ^ ((n & 7) << 4);
      *(u32x2*)((char*)Xl + n * 512 + wb) = o2;
    }
  }
  __syncthreads();

  const f32x4 fz = {0.f, 0.f, 0.f, 0.f};
  bf16* lb = Vb[wave];
  for (int og = 0; og < 3; ++og) {
    const int ot0 = wo * 12 + og * 4;
    f32x4 acc[4][4];  // [nt][oi]
#pragma unroll
    for (int nt = 0; nt < 4; ++nt)
#pragma unroll
      for (int oi = 0; oi < 4; ++oi) acc[nt][oi] = fz;
#pragma unroll
    for (int kc = 0; kc < 8; ++kc) {
      bf16x8 afr[4], bfr[4];
#pragma unroll
      for (int nt = 0; nt < 4; ++nt) {
        int nn = wm * 64 + nt * 16 + l15;
        int wb = (kc * 64 + l4 * 16) ^ ((nn & 7) << 4);
        afr[nt] = *(const bf16x8*)((const char*)Xl + nn * 512 + wb);
      }
#pragma unroll
      for (int oi = 0; oi < 4; ++oi)
        bfr[oi] = *(const bf16x8*)(Wf + ((((ot0 + oi) * 8) + kc) * 64 + lane) * 8);
#pragma unroll
      for (int nt = 0; nt < 4; ++nt)
#pragma unroll
        for (int oi = 0; oi < 4; ++oi)
          acc[nt][oi] = MFMA16(afr[nt], bfr[oi], acc[nt][oi]);
    }
    // ---- batched epilogue for this 64x64 group ----
#pragma unroll
    for (int oi = 0; oi < 4; ++oi) {
      int ot = ot0 + oi;
      int o = ot * 16 + l15;  // B col = l15
      float bias = qb[o];
      int seg = o >> 8;
      int h = (o >> 5) & 7;
      int d = o & 31;
      int base = (b * 8 + h) * 8192;
#pragma unroll
      for (int pr = 0; pr < 2; ++pr) {
        f32x4 acc0 = acc[2 * pr][oi], acc1 = acc[2 * pr + 1][oi];
        int n0p = n0w + pr * 32;
        if (seg == 0) {
          bf16* dq = q + base + d;
#pragma unroll
          for (int nt = 0; nt < 2; ++nt)
#pragma unroll
            for (int r = 0; r < 4; ++r) {
              int n = n0p + nt * 16 + l4 * 4 + r;
              float v = nt ? acc1[r] : acc0[r];
              dq[n * 32] = (bf16)((v + bias) * 0.17677669529663687f);
            }
        } else if (seg == 1) {
          bf16* dk = kk + base + d;
#pragma unroll
          for (int nt = 0; nt < 2; ++nt)
#pragma unroll
            for (int r = 0; r < 4; ++r) {
              int n = n0p + nt * 16 + l4 * 4 + r;
              float v = nt ? acc1[r] : acc0[r];
              dk[n * 32] = (bf16)(v + bias);
            }
        } else {
          // v: transpose 16d x 32n tile through LDS -> contiguous-n 64B rows
#pragma unroll
          for (int nt = 0; nt < 2; ++nt) {
            f32x4 a = nt ? acc1 : acc0;
            *(u32*)(lb + l15 * 36 + nt * 16 + l4 * 4) =
                pack2(a[0] + bias, a[1] + bias);
            *(u32*)(lb + l15 * 36 + nt * 16 + l4 * 4 + 2) =
                pack2(a[2] + bias, a[3] + bias);
          }
          asm volatile("s_waitcnt lgkmcnt(0)" ::: "memory");
          __builtin_amdgcn_sched_barrier(0);
          int dl = lane >> 2, chv = lane & 3;
          bf16x4 rv0 = *(bf16x4*)(lb + dl * 36 + chv * 8);
          bf16x4 rv1 = *(bf16x4*)(lb + dl * 36 + chv * 8 + 4);
          asm volatile("s_waitcnt lgkmcnt(0)" ::: "memory");
          __builtin_amdgcn_sched_barrier(0);
          int d2 = (ot & 1) * 16 + dl;
          bf16* dv2 = vT + base + d2 * 256 + n0p + chv * 8;
          *(bf16x4*)dv2 = rv0;
          *(bf16x4*)(dv2 + 4) = rv1;
        }
      }
    }
  }
}

// ---------------- attention per (b, h): 32x32 swapped-operand scheme ----------------
__global__ __launch_bounds__(256, 2) void k_attn(
    const bf16* __restrict__ q, const bf16* __restrict__ kk,
    const bf16* __restrict__ vT, const bf16* __restrict__ Bsw,
    bf16* __restrict__ ao) {
  __shared__ bf16 Kl[256 * 36];    // 18,432 B
  __shared__ bf16 Ob[4][32 * 36];  // 9,216 B: per-wave output transpose bounce
  const int bh = blockIdx.x;
  const int b = bh >> 3, h = bh & 7;
  const int tid = threadIdx.x;
  const int lane = tid & 63, wave = tid >> 6;
  const int l31 = lane & 31, hi = lane >> 5;

  const bf16* Kg = kk + bh * 8192;
#pragma unroll
  for (int i = 0; i < 4; ++i) {
    int t = tid + i * 256;
    int n = t >> 2, dc = t & 3;
    *(bf16x8*)(Kl + n * 36 + dc * 8) = *(const bf16x8*)(Kg + n * 32 + dc * 8);
  }
  __syncthreads();

  const bf16* Vg = vT + bh * 8192;
  bf16* ob = Ob[wave];
  for (int qi = 0; qi < 2; ++qi) {
    const int qt = wave * 2 + qi, q0 = qt * 32;
    bf16x8 qf0 = *(const bf16x8*)(q + bh * 8192 + (q0 + l31) * 32 + hi * 8);
    bf16x8 qf1 = *(const bf16x8*)(q + bh * 8192 + (q0 + l31) * 32 + 16 + hi * 8);
    const bf16* bq = Bsw + (h * 8 + qt) * 8192 + lane * 16;
    f32x16 s[8];
#pragma unroll
    for (int kt2 = 0; kt2 < 8; ++kt2) {
      bf16x8 ba = *(const bf16x8*)(bq + kt2 * 1024);
      bf16x8 bbv = *(const bf16x8*)(bq + kt2 * 1024 + 8);
      f32x16 acc;
#pragma unroll
      for (int i = 0; i < 8; ++i) {
        acc[i] = (float)ba[i];
        acc[8 + i] = (float)bbv[i];
      }
      bf16x8 kf0 = *(const bf16x8*)(Kl + (kt2 * 32 + l31) * 36 + hi * 8);
      bf16x8 kf1 = *(const bf16x8*)(Kl + (kt2 * 32 + l31) * 36 + 16 + hi * 8);
      acc = MFMA32(kf0, qf0, acc);
      acc = MFMA32(kf1, qf1, acc);
      s[kt2] = acc;  // S^T[key=kt2*32+(reg&3)+8*(reg>>2)+4*hi][n=q0+l31]
    }
    float m = -1e30f;
#pragma unroll
    for (int kt2 = 0; kt2 < 8; ++kt2)
#pragma unroll
      for (int i = 0; i < 16; ++i) m = fmaxf(m, s[kt2][i]);
    m = fmaxf(m, __shfl_xor(m, 32));
    float sum = 0.f;
#pragma unroll
    for (int kt2 = 0; kt2 < 8; ++kt2)
#pragma unroll
      for (int i = 0; i < 16; ++i) {
        float e = __expf(s[kt2][i] - m);
        s[kt2][i] = e;
        sum += e;
      }
    sum += __shfl_xor(sum, 32);
    const float inv = 1.f / sum;

    f32x16 o;
#pragma unroll
    for (int i = 0; i < 16; ++i) o[i] = 0.f;
#pragma unroll
    for (int kt2 = 0; kt2 < 8; ++kt2) {
      u32 lo[4], hw[4];
#pragma unroll
      for (int qq = 0; qq < 4; ++qq) {
        lo[qq] = pack2(s[kt2][4 * qq] * inv, s[kt2][4 * qq + 1] * inv);
        hw[qq] = pack2(s[kt2][4 * qq + 2] * inv, s[kt2][4 * qq + 3] * inv);
      }
#pragma unroll
      for (int sb = 0; sb < 2; ++sb) {
        u32 keep_lo = hi ? lo[2 * sb + 1] : lo[2 * sb];
        u32 keep_hi = hi ? hw[2 * sb + 1] : hw[2 * sb];
        u32 send_lo = hi ? lo[2 * sb] : lo[2 * sb + 1];
        u32 send_hi = hi ? hw[2 * sb] : hw[2 * sb + 1];
        u32 rlo = __shfl_xor(send_lo, 32);
        u32 rhi = __shfl_xor(send_hi, 32);
        u32x4 bw;
        bw[0] = hi ? rlo : keep_lo;
        bw[1] = hi ? rhi : keep_hi;
        bw[2] = hi ? keep_lo : rlo;
        bw[3] = hi ? keep_hi : rhi;
        bf16x8 pf = __builtin_bit_cast(bf16x8, bw);
        bf16x8 vf = *(const bf16x8*)(Vg + l31 * 256 + kt2 * 32 + sb * 16 + hi * 8);
        o = MFMA32(vf, pf, o);
      }
    }
#pragma unroll
    for (int qq = 0; qq < 4; ++qq) {
      *(u32*)(ob + l31 * 36 + 8 * qq + 4 * hi) = pack2(o[4 * qq], o[4 * qq + 1]);
      *(u32*)(ob + l31 * 36 + 8 * qq + 4 * hi + 2) = pack2(o[4 * qq + 2], o[4 * qq + 3]);
    }
    asm volatile("s_waitcnt lgkmcnt(0)" ::: "memory");
    __builtin_amdgcn_sched_barrier(0);
    int n2 = lane >> 1, ch = lane & 1;
    bf16x4 r0 = *(bf16x4*)(ob + n2 * 36 + ch * 16);
    bf16x4 r1 = *(bf16x4*)(ob + n2 * 36 + ch * 16 + 4);
    bf16x4 r2 = *(bf16x4*)(ob + n2 * 36 + ch * 16 + 8);
    bf16x4 r3 = *(bf16x4*)(ob + n2 * 36 + ch * 16 + 12);
    asm volatile("s_waitcnt lgkmcnt(0)" ::: "memory");
    __builtin_amdgcn_sched_barrier(0);
    bf16* dst = ao + (b * 256 + q0 + n2) * 256 + h * 32 + ch * 16;
    *(bf16x4*)dst = r0;
    *(bf16x4*)(dst + 4) = r1;
    *(bf16x4*)(dst + 8) = r2;
    *(bf16x4*)(dst + 12) = r3;
  }
}

// ---------------- output projection, written transposed (b, o, n) ----------------
__global__ __launch_bounds__(256) void k_proj(
    const bf16* __restrict__ ao, const bf16* __restrict__ Wp,
    const float* __restrict__ pb, float* __restrict__ out) {
  const int i = blockIdx.x;
  const int flat = (i & 7) * 128 + (i >> 3);  // XCD-bijective swizzle
  const int b = flat >> 2, oc = flat & 3;
  const int lane = threadIdx.x & 63, wave = threadIdx.x >> 6;
  const int l15 = lane & 15, l4 = lane >> 4;
  const int otile = oc * 4 + wave;
  bf16x8 af[8];  // A = proj_w: row o = l15, k = c
  const bf16* wr = Wp + (otile * 16 + l15) * 256 + l4 * 8;
#pragma unroll
  for (int kc = 0; kc < 8; ++kc) af[kc] = *(const bf16x8*)(wr + kc * 32);
  float bias[4];
#pragma unroll
  for (int r = 0; r < 4; ++r) bias[r] = pb[otile * 16 + l4 * 4 + r];
  const bf16* aob = ao + b * 65536;
  float* outb = out + b * 65536 + otile * 16 * 256;
  const f32x4 fz = {0.f, 0.f, 0.f, 0.f};
  for (int nt = 0; nt < 16; ++nt) {
    f32x4 acc = fz;
#pragma unroll
    for (int kc = 0; kc < 8; ++kc) {
      bf16x8 bfr = *(const bf16x8*)(aob + (nt * 16 + l15) * 256 + kc * 32 + l4 * 8);
      acc = MFMA16(af[kc], bfr, acc);
    }
#pragma unroll
    for (int r = 0; r < 4; ++r)
      outb[(l4 * 4 + r) * 256 + nt * 16 + l15] = acc[r] + bias[r];
  }
}

extern "C" void kernel_launch(void* const* d_in, const int* in_sizes, int n_in,
                              void* d_out, int out_size, void* d_ws, size_t ws_size,
                              hipStream_t stream) {
  const float* x    = (const float*)d_in[0];
  const float* qkvw = (const float*)d_in[1];
  const float* qkvb = (const float*)d_in[2];
  const float* pjw  = (const float*)d_in[3];
  const float* pjb  = (const float*)d_in[4];
  const float* ppw  = (const float*)d_in[5];
  const float* ppb  = (const float*)d_in[6];
  const float* g1 = (const float*)d_in[7];   const float* b1 = (const float*)d_in[8];
  const float* f1w = (const float*)d_in[9];  const float* f1b = (const float*)d_in[10];
  const float* g2 = (const float*)d_in[11];  const float* b2 = (const float*)d_in[12];
  const float* f2w = (const float*)d_in[13]; const float* f2b = (const float*)d_in[14];
  const float* g3 = (const float*)d_in[15];  const float* b3 = (const float*)d_in[16];
  const float* f3w = (const float*)d_in[17]; const float* f3b = (const float*)d_in[18];
  float* out = (float*)d_out;

  // ws: q | k | vT | ao (16,777,216 bf16 each) | ptab 8192 f32 | Wf 196608 bf16
  //     | Wproj 65536 bf16 | Bsw 524288 bf16
  bf16* wsq  = (bf16*)d_ws;
  bf16* wsk  = wsq + 16777216;
  bf16* wsv  = wsk + 16777216;
  bf16* wsao = wsv + 16777216;
  float* ptab = (float*)(wsao + 16777216);
  bf16* wqkv = (bf16*)(ptab + 8192);
  bf16* wpj  = wqkv + 196608;
  bf16* bsw  = wpj + 65536;

  hipLaunchKernelGGL(k_wpack, dim3(96), dim3(256), 0, stream, qkvw, wqkv);
  hipLaunchKernelGGL(k_cvt, dim3(64), dim3(256), 0, stream, pjw, wpj, 16384);
  hipLaunchKernelGGL(k_dpb, dim3(4), dim3(256), 0, stream, ppw, ppb, g1, b1, f1w,
                     f1b, g2, b2, f2w, f2b, g3, b3, f3w, f3b, ptab);
  hipLaunchKernelGGL(k_bias, dim3(128), dim3(256), 0, stream, ptab, bsw);
  hipLaunchKernelGGL(k_qkv, dim3(512), dim3(512), 0, stream, x, wqkv, qkvb, wsq,
                     wsk, wsv);
  hipLaunchKernelGGL(k_attn, dim3(2048), dim3(256), 0, stream, wsq, wsk, wsv,
                     bsw, wsao);
  hipLaunchKernelGGL(k_proj, dim3(1024), dim3(256), 0, stream, wsao, wpj, pjb, out);
}